// Round 4
// baseline (1231.176 us; speedup 1.0000x reference)
//
#include <hip/hip_runtime.h>
#include <hip/hip_fp16.h>

typedef unsigned int u32;
typedef unsigned long long u64;

// ---------------- problem sizes ----------------
#define B 8
#define S 160
#define H 128
#define H3 384
#define G4 512
#define CG 1536
#define WIN 300
#define VIN 35
#define AIN 74

// ---------------- workspace layout (float-word offsets) ----------------
#define XG_W   0
#define XG_V   (XG_W + B*S*G4)
#define XG_A   (XG_V + B*S*G4)
#define HS_W   (XG_A + B*S*G4)
#define HS_V   (HS_W + B*S*H)
#define HS_A   (HS_V + B*S*H)
#define S_VW   (HS_A + B*S*H)
#define T_VW   (S_VW + B*S*H)
#define S_AW   (T_VW + B*S*H)
#define T_AW   (S_AW + B*S*H)
#define C_X    (T_AW + B*S*H)
#define S_SA   (C_X + B*S*H3)
#define WIHT_W (S_SA + B*S*H3)
#define WIHT_V (WIHT_W + WIN*G4)
#define WIHT_A (WIHT_V + VIN*G4)
#define WIHT_C (WIHT_A + AIN*G4)
#define SAT_S  (WIHT_C + H3*CG)
#define SAT_T  (SAT_S + H3*H3)
#define VW_ST  (SAT_T + H3*H3)
#define VW_TT  (VW_ST + H*H)
#define AW_ST  (VW_TT + H*H)
#define AW_TT  (AW_ST + H*H)
#define BSUM_W (AW_TT + H*H)
#define BSUM_V (BSUM_W + G4)
#define BSUM_A (BSUM_V + G4)
#define BSUM_C (BSUM_A + G4)
#define VCOMP  (BSUM_C + CG)
#define ACOMP  (VCOMP + B*H)
#define C_OUT  (ACOMP + B*H)
// u32 regions
#define XGC16  (C_OUT + B*H3)
// XGC16: f16 [t][gate][b]  (S*CG*8 halves)
#define WRES   (XGC16 + B*S*CG/2)
// WRES: u32 idx = ((p*64 + r)*8 + s)*24 + j ; p block, r row-in-block, s dim-slice
#define CHS16  (WRES + CG*H3/2)
// CHS16: u32 [b][t][192]  (c_hs f16 pairs)
#define H_X    (CHS16 + B*S*H3/2)
// H_X: u64 slots [par][b][192] = 2*1536 u64 (seq<<32 | h-pair), poison-safe monotone seq

// ---------------- output layout ----------------
#define O_VATT  8
#define O_VSOFT (8 + B*S*S)
#define O_AATT  (O_VSOFT + B*S)
#define O_ASOFT (O_AATT + B*S*S)

// repetition macros
#define REP16(M) M(0)M(1)M(2)M(3)M(4)M(5)M(6)M(7)M(8)M(9)M(10)M(11)M(12)M(13)M(14)M(15)

// ---------------- helpers ----------------
__device__ __forceinline__ float sigf(float x){ return 1.f/(1.f+__expf(-x)); }
__device__ __forceinline__ float tanhfast(float x){ float e=__expf(2.f*x); return 1.f - 2.f/(e+1.f); }
__device__ __forceinline__ float wred_sum(float x){
#pragma unroll
  for (int o=32;o;o>>=1) x += __shfl_xor(x,o);
  return x;
}
__device__ __forceinline__ float wred_max(float x){
#pragma unroll
  for (int o=32;o;o>>=1) x = fmaxf(x,__shfl_xor(x,o));
  return x;
}
__device__ __forceinline__ u32 packh2(float lo, float hi){
  __half a=__float2half_rn(lo), b=__float2half_rn(hi);
  return ((u32)__half_as_ushort(b)<<16) | (u32)__half_as_ushort(a);
}

typedef _Float16 h2v __attribute__((ext_vector_type(2)));
#if defined(__has_builtin)
#if __has_builtin(__builtin_amdgcn_fdot2)
#define HAVE_FDOT2 1
#endif
#endif
__device__ __forceinline__ float fdot2f(u32 w, u32 h, float acc){
#ifdef HAVE_FDOT2
  return __builtin_amdgcn_fdot2(__builtin_bit_cast(h2v,w), __builtin_bit_cast(h2v,h), acc, false);
#else
  h2v a=__builtin_bit_cast(h2v,w), b=__builtin_bit_cast(h2v,h);
  return acc + (float)a.x*(float)b.x + (float)a.y*(float)b.y;
#endif
}

// ---------------- K0: prep (transposes, bias sums, f16 packs) ----------------
#define PREP_TOT (3*G4 + CG + WIN*G4 + VIN*G4 + AIN*G4 + H3*CG + 2*H3*H3 + 4*H*H + CG*H3/2)
__global__ void k0_prep(float* __restrict__ ws, u32* __restrict__ wsu,
    const float* __restrict__ wWih, const float* __restrict__ wbih, const float* __restrict__ wbhh,
    const float* __restrict__ vWih, const float* __restrict__ vbih, const float* __restrict__ vbhh,
    const float* __restrict__ aWih, const float* __restrict__ abih, const float* __restrict__ abhh,
    const float* __restrict__ cWih, const float* __restrict__ cWhh, const float* __restrict__ cbih, const float* __restrict__ cbhh,
    const float* __restrict__ vwW1, const float* __restrict__ awW1, const float* __restrict__ saW1)
{
  int idx = blockIdx.x*256 + threadIdx.x;
  if (idx >= PREP_TOT) return;
  if (idx < G4){ ws[BSUM_W+idx]=wbih[idx]+wbhh[idx]; return; } idx -= G4;
  if (idx < G4){ ws[BSUM_V+idx]=vbih[idx]+vbhh[idx]; return; } idx -= G4;
  if (idx < G4){ ws[BSUM_A+idx]=abih[idx]+abhh[idx]; return; } idx -= G4;
  if (idx < CG){ ws[BSUM_C+idx]=cbih[idx]+cbhh[idx]; return; } idx -= CG;
  if (idx < WIN*G4){ int k=idx/G4,g=idx%G4; ws[WIHT_W+idx]=wWih[g*WIN+k]; return; } idx -= WIN*G4;
  if (idx < VIN*G4){ int k=idx/G4,g=idx%G4; ws[WIHT_V+idx]=vWih[g*VIN+k]; return; } idx -= VIN*G4;
  if (idx < AIN*G4){ int k=idx/G4,g=idx%G4; ws[WIHT_A+idx]=aWih[g*AIN+k]; return; } idx -= AIN*G4;
  if (idx < H3*CG){ int k=idx/CG,g=idx%CG; ws[WIHT_C+idx]=cWih[g*H3+k]; return; } idx -= H3*CG;
  if (idx < H3*H3){ int k=idx/H3,d=idx%H3; ws[SAT_S+idx]=saW1[d*(2*H3)+k]; return; } idx -= H3*H3;
  if (idx < H3*H3){ int k=idx/H3,d=idx%H3; ws[SAT_T+idx]=saW1[d*(2*H3)+H3+k]; return; } idx -= H3*H3;
  if (idx < H*H){ int k=idx/H,d=idx%H; ws[VW_ST+idx]=vwW1[d*(2*H)+k]; return; } idx -= H*H;
  if (idx < H*H){ int k=idx/H,d=idx%H; ws[VW_TT+idx]=vwW1[d*(2*H)+H+k]; return; } idx -= H*H;
  if (idx < H*H){ int k=idx/H,d=idx%H; ws[AW_ST+idx]=awW1[d*(2*H)+k]; return; } idx -= H*H;
  if (idx < H*H){ int k=idx/H,d=idx%H; ws[AW_TT+idx]=awW1[d*(2*H)+H+k]; return; } idx -= H*H;
  // WRES: c_Whh -> f16x2 in k6's per-thread layout
  {
    int j = idx % 24; int th = idx / 24;
    int s = th & 7; int r = (th >> 3) & 63; int p = th >> 9;
    int g3 = r >> 4, m = r & 15;
    int grow = g3*H3 + p*16 + m;
    int k2 = s*24 + j;
    wsu[WRES+idx] = packh2(cWhh[(size_t)grow*H3 + 2*k2], cWhh[(size_t)grow*H3 + 2*k2 + 1]);
  }
}

// ---------------- K1: input projections xg for w/v/a LSTMs ----------------
// grid: 3 * B * (S/8) = 480 blocks, 256 threads
__global__ void k1_xg(float* __restrict__ ws,
    const float* __restrict__ xw, const float* __restrict__ xv, const float* __restrict__ xa)
{
  int bid = blockIdx.x;
  int lstm = bid/160; int rem = bid%160; int b = rem/20; int s0 = (rem%20)*8;
  int in_dim; const float* x; const float* wT; const float* bs; float* xg;
  if (lstm==0){ in_dim=WIN; x=xw; wT=ws+WIHT_W; bs=ws+BSUM_W; xg=ws+XG_W; }
  else if (lstm==1){ in_dim=VIN; x=xv; wT=ws+WIHT_V; bs=ws+BSUM_V; xg=ws+XG_V; }
  else { in_dim=AIN; x=xa; wT=ws+WIHT_A; bs=ws+BSUM_A; xg=ws+XG_A; }
  __shared__ float xt[8][WIN];
  int tid = threadIdx.x;
  for (int i=tid; i<8*in_dim; i+=256){ int r=i/in_dim, k=i%in_dim; xt[r][k] = x[((size_t)(b*S+s0+r))*in_dim + k]; }
  __syncthreads();
  float acc0[8], acc1[8];
  float b0 = bs[tid], b1 = bs[tid+256];
#pragma unroll
  for (int r=0;r<8;r++){ acc0[r]=b0; acc1[r]=b1; }
  for (int k=0;k<in_dim;k++){
    float w0 = wT[k*G4 + tid], w1 = wT[k*G4 + 256 + tid];
#pragma unroll
    for (int r=0;r<8;r++){ float xx = xt[r][k]; acc0[r] = fmaf(xx,w0,acc0[r]); acc1[r] = fmaf(xx,w1,acc1[r]); }
  }
#pragma unroll
  for (int r=0;r<8;r++){
    size_t ro = (size_t)(b*S+s0+r)*G4;
    xg[ro + tid] = acc0[r];
    xg[ro + 256 + tid] = acc1[r];
  }
}

// ---------------- K2: w/v/a LSTM recurrences ----------------
// grid 24 blocks (lstm,batch), 1024 threads; 2 threads per gate row, 64 f32
// weights each = 16 named float4 (64 VGPR) -> fits default budget, no spill.
__global__ __launch_bounds__(1024) void k2_lstm(float* __restrict__ ws,
    const float* __restrict__ wWhh, const float* __restrict__ vWhh, const float* __restrict__ aWhh)
{
  int lstm = blockIdx.x >> 3, b = blockIdx.x & 7;
  const float* xg; const float* whh; float* hs; float* cx = nullptr;
  if (lstm==0){ xg=ws+XG_W; whh=wWhh; hs=ws+HS_W; cx=ws+C_X; }
  else if (lstm==1){ xg=ws+XG_V; whh=vWhh; hs=ws+HS_V; }
  else { xg=ws+XG_A; whh=aWhh; hs=ws+HS_A; }
  int tid = threadIdx.x;
  int row = tid >> 1, s = tid & 1;
  const float4* wb = (const float4*)(whh + (size_t)row*H + s*64);
#define K2_LD(i) float4 w##i = wb[i];
  REP16(K2_LD)
  __shared__ __align__(16) float hbuf[H];
  __shared__ float gsum[G4];
  float c_reg = 0.f;
  if (tid < H) hbuf[tid] = 0.f;
  const float* xgb = xg + (size_t)b*S*G4;
  float* hsb = hs + (size_t)b*S*H;
  float* cxb = cx ? cx + (size_t)b*S*H3 : nullptr;
  float xg_cur = xgb[row];
  __syncthreads();
  const float4* h4p = (const float4*)(hbuf + s*64);
  for (int t=0;t<S;t++){
    float acc = 0.f;
#define K2_FMA(i) { float4 h4 = h4p[i]; acc = fmaf(w##i.x,h4.x,acc); acc = fmaf(w##i.y,h4.y,acc); acc = fmaf(w##i.z,h4.z,acc); acc = fmaf(w##i.w,h4.w,acc); }
    REP16(K2_FMA)
    acc += __shfl_xor(acc, 1);
    float xg_nxt = (t+1<S) ? xgb[(size_t)(t+1)*G4 + row] : 0.f;
    if (s == 0) gsum[row] = acc + xg_cur;
    __syncthreads();
    if (tid < H){
      float gi=gsum[tid], gf=gsum[H+tid], gg=gsum[2*H+tid], go=gsum[3*H+tid];
      c_reg = sigf(gf)*c_reg + sigf(gi)*tanhfast(gg);
      float h = sigf(go)*tanhfast(c_reg);
      hbuf[tid] = h;
      hsb[(size_t)t*H + tid] = h;
      if (cxb) cxb[(size_t)t*H3 + tid] = h;
    }
    xg_cur = xg_nxt;
    __syncthreads();
  }
}

// ---------------- K3a: attention projections (s/t for vw and aw) ----------------
// grid 4*B*(S/8)=640, 128 threads
__global__ void k3a_proj(float* __restrict__ ws, const float* __restrict__ vwb1, const float* __restrict__ awb1)
{
  int bid = blockIdx.x;
  int p = bid/160; int rem = bid%160; int b = rem/20; int s0 = (rem%20)*8;
  const float* src; const float* wT; const float* bias=nullptr; float* dst;
  if (p==0){ src=ws+HS_V; wT=ws+VW_ST; dst=ws+S_VW; }
  else if (p==1){ src=ws+HS_W; wT=ws+VW_TT; bias=vwb1; dst=ws+T_VW; }
  else if (p==2){ src=ws+HS_A; wT=ws+AW_ST; dst=ws+S_AW; }
  else { src=ws+HS_W; wT=ws+AW_TT; bias=awb1; dst=ws+T_AW; }
  __shared__ float xr[8][H];
  int tid = threadIdx.x;
  for (int i=tid;i<8*H;i+=128){ int r=i>>7, k=i&127; xr[r][k] = src[(size_t)(b*S+s0+r)*H + k]; }
  __syncthreads();
  float acc[8];
  float bv = bias ? bias[tid] : 0.f;
#pragma unroll
  for (int r=0;r<8;r++) acc[r]=bv;
  for (int k=0;k<H;k++){
    float wv = wT[k*H + tid];
#pragma unroll
    for (int r=0;r<8;r++) acc[r] = fmaf(xr[r][k], wv, acc[r]);
  }
#pragma unroll
  for (int r=0;r<8;r++) dst[(size_t)(b*S+s0+r)*H + tid] = acc[r];
}

// ---------------- K3b: vw/aw cross-attention (scores, softmax, out) ----------------
// grid 2*B*S/4 = 640 blocks of 256 (wave per (A,b,w) row)
__global__ void k3b_attn(float* __restrict__ ws, float* __restrict__ dout,
    const int* __restrict__ lengths, const float* __restrict__ vww2, const float* __restrict__ aww2)
{
  int wid = threadIdx.x >> 6, lane = threadIdx.x & 63;
  int row = blockIdx.x*4 + wid;
  int A = row / (B*S); int rem = row % (B*S); int b = rem / S; int w = rem % S;
  const float* sp = ws + (A? S_AW : S_VW) + (size_t)(b*S)*H;
  const float* tp = ws + (A? T_AW : T_VW) + (size_t)(b*S + w)*H;
  const float* w2 = A? aww2 : vww2;
  const float* src = ws + (A? HS_A : HS_V) + (size_t)(b*S)*H;
  float* attw = dout + (A? O_AATT : O_VATT) + (size_t)b*S*S + (size_t)w*S;
  int len = lengths[b];
  __shared__ float sc[4][S];
  float2 t2 = ((const float2*)tp)[lane];
  float2 w22 = ((const float2*)w2)[lane];
  for (int v=0; v<S; v++){
    float2 s2 = ((const float2*)(sp + (size_t)v*H))[lane];
    float x0 = tanhfast(t2.x + s2.x), x1 = tanhfast(t2.y + s2.y);
    float p = wred_sum(x0*w22.x + x1*w22.y);
    if (lane==0) sc[wid][v] = p;
  }
  __syncthreads();
  float m0 = (lane      < len)? sc[wid][lane]     : 0.f;
  float m1 = (lane+64   < len)? sc[wid][lane+64]  : 0.f;
  float m2 = (lane<32) ? ((lane+128 < len)? sc[wid][lane+128] : 0.f) : -1e30f;
  float m = wred_max(fmaxf(fmaxf(m0,m1),m2));
  float e0 = __expf(m0-m), e1 = __expf(m1-m), e2 = (lane<32)? __expf(m2-m) : 0.f;
  float inv = 1.f / wred_sum(e0+e1+e2);
  e0*=inv; e1*=inv; e2*=inv;
  sc[wid][lane] = e0; sc[wid][lane+64] = e1; if (lane<32) sc[wid][128+lane] = e2;
  attw[lane] = e0; attw[lane+64] = e1; if (lane<32) attw[128+lane] = e2;
  __syncthreads();
  float2 acc; acc.x=0.f; acc.y=0.f;
  for (int v=0; v<S; v++){
    float wg = sc[wid][v];
    float2 sv = ((const float2*)(src + (size_t)v*H))[lane];
    acc.x = fmaf(wg, sv.x, acc.x); acc.y = fmaf(wg, sv.y, acc.y);
  }
  float* cxr = ws + C_X + (size_t)(b*S + w)*H3 + (A? 2*H : H);
  ((float2*)cxr)[lane] = acc;
}

// ---------------- K4: soft attention (v and a) ----------------
// grid 16 (A*8+b), 256 threads
__global__ void k4_soft(float* __restrict__ ws, float* __restrict__ dout,
    const float* __restrict__ mpw, const float* __restrict__ mpb)
{
  int A = blockIdx.x >> 3, b = blockIdx.x & 7;
  const float* reps = ws + (A? HS_A : HS_V) + (size_t)(b*S)*H;
  float* softw = dout + (A? O_ASOFT : O_VSOFT) + b*S;
  float* comp = ws + (A? ACOMP : VCOMP) + b*H;
  __shared__ float sc[S]; __shared__ float wg[S];
  int wid = threadIdx.x >> 6, lane = threadIdx.x & 63;
  float bb = mpb[0];
  for (int s=wid; s<S; s+=4){
    float2 r2 = ((const float2*)(reps + (size_t)s*H))[lane];
    float2 m2 = ((const float2*)mpw)[lane];
    float p = wred_sum(r2.x*m2.x + r2.y*m2.y);
    if (lane==0) sc[s] = p + bb;
  }
  __syncthreads();
  if (threadIdx.x < 64){
    float m0 = sc[lane], m1 = sc[lane+64], m2 = (lane<32)? sc[lane+128] : -1e30f;
    float m = wred_max(fmaxf(fmaxf(m0,m1),m2));
    float e0=__expf(m0-m), e1=__expf(m1-m), e2=(lane<32)?__expf(m2-m):0.f;
    float inv = 1.f / wred_sum(e0+e1+e2);
    e0*=inv; e1*=inv; e2*=inv;
    wg[lane]=e0; wg[lane+64]=e1; if (lane<32) wg[128+lane]=e2;
    softw[lane]=e0; softw[lane+64]=e1; if (lane<32) softw[128+lane]=e2;
  }
  __syncthreads();
  if (threadIdx.x < H){
    float acc=0.f;
    for (int s=0;s<S;s++) acc = fmaf(wg[s], reps[(size_t)s*H + threadIdx.x], acc);
    comp[threadIdx.x] = acc;
  }
}

// ---------------- K5: c-LSTM input projection -> xgc [t][gate][b] f16 ----------------
// grid B*40 (s-tile 4), 512 threads
__global__ void k5_xgc(float* __restrict__ ws, u32* __restrict__ wsu)
{
  int b = blockIdx.x/40; int s0 = (blockIdx.x%40)*4;
  const float* cxb = ws + C_X + (size_t)(b*S+s0)*H3;
  const float* wT = ws + WIHT_C;
  const float* bs = ws + BSUM_C;
  __half* xgc = (__half*)(wsu + XGC16);
  __shared__ float xr[4][H3];
  int tid = threadIdx.x;
  for (int i=tid;i<4*H3;i+=512){ int r=i/H3, k=i%H3; xr[r][k]=cxb[(size_t)r*H3+k]; }
  __syncthreads();
  float acc[4][3];
  float b0=bs[tid], b1=bs[tid+512], b2=bs[tid+1024];
#pragma unroll
  for (int r=0;r<4;r++){ acc[r][0]=b0; acc[r][1]=b1; acc[r][2]=b2; }
  for (int k=0;k<H3;k++){
    float w0=wT[(size_t)k*CG+tid], w1=wT[(size_t)k*CG+512+tid], w2v=wT[(size_t)k*CG+1024+tid];
#pragma unroll
    for (int r=0;r<4;r++){
      float xx = xr[r][k];
      acc[r][0]=fmaf(xx,w0,acc[r][0]); acc[r][1]=fmaf(xx,w1,acc[r][1]); acc[r][2]=fmaf(xx,w2v,acc[r][2]);
    }
  }
#pragma unroll
  for (int r=0;r<4;r++){
#pragma unroll
    for (int part=0;part<3;part++){
      int gate = part*512 + tid;
      xgc[((size_t)(s0+r)*CG + gate)*8 + b] = __float2half_rn(acc[r][part]);
    }
  }
}

// ---------------- K6: c-LSTM recurrence, all-batch blocks ----------------
// 24 blocks; block p owns cells [p*16,p*16+16) (64 gate rows) for ALL 8 batches.
// Thread (r,s): row r, dim-slice s -> 6 uint4 weights (24 VGPR, allocator-proof).
// Dot: 8 batches x 24 fdot2; 3-round shuffle tree leaves thread with batch s's gate.
// Exchange: 128 update-threads publish seq-tagged u64 pairs; waves 2-7 poll all
// 1536 slots (4/thread). Monotone seq + parity + harness re-poison => race-free.
__global__ __launch_bounds__(512) void k6_clstm(float* __restrict__ ws, u32* __restrict__ wsu)
{
  int p = blockIdx.x;
  int tid = threadIdx.x;
  int r = tid >> 3, s = tid & 7, s6 = s*6;
  int g3 = r >> 4, m = r & 15;
  int grow = g3*H3 + p*16 + m;
  const __half* xgc = (const __half*)(wsu + XGC16);
  u32* chs = wsu + CHS16;
  u64* slots = (u64*)(wsu + H_X);
  const uint4* wb = ((const uint4*)(wsu + WRES)) + ((size_t)(p*64 + r)*8 + s)*6;
  uint4 w0=wb[0], w1=wb[1], w2=wb[2], w3=wb[3], w4=wb[4], w5=wb[5];
  __shared__ __align__(16) u32 h2[8*192];
  __shared__ float gsum[64*9];
  float c_reg = 0.f;
  for (int i=tid;i<8*192;i+=512) h2[i]=0u;
  float xg_cur = __half2float(xgc[(size_t)grow*8 + s]);
  __syncthreads();
  const uint4* h2q = (const uint4*)h2;
  int s0b = s&1, s1b = s&2, s2b = s&4;
  for (int t=0;t<S;t++){
#define K6_DOT(bi, dst) { const uint4* hb = h2q + (bi)*48 + s6; \
    uint4 x0=hb[0],x1=hb[1],x2=hb[2],x3=hb[3],x4=hb[4],x5=hb[5]; \
    float aA=0.f,aB=0.f; \
    aA=fdot2f(w0.x,x0.x,aA); aB=fdot2f(w0.y,x0.y,aB); aA=fdot2f(w0.z,x0.z,aA); aB=fdot2f(w0.w,x0.w,aB); \
    aA=fdot2f(w1.x,x1.x,aA); aB=fdot2f(w1.y,x1.y,aB); aA=fdot2f(w1.z,x1.z,aA); aB=fdot2f(w1.w,x1.w,aB); \
    aA=fdot2f(w2.x,x2.x,aA); aB=fdot2f(w2.y,x2.y,aB); aA=fdot2f(w2.z,x2.z,aA); aB=fdot2f(w2.w,x2.w,aB); \
    aA=fdot2f(w3.x,x3.x,aA); aB=fdot2f(w3.y,x3.y,aB); aA=fdot2f(w3.z,x3.z,aA); aB=fdot2f(w3.w,x3.w,aB); \
    aA=fdot2f(w4.x,x4.x,aA); aB=fdot2f(w4.y,x4.y,aB); aA=fdot2f(w4.z,x4.z,aA); aB=fdot2f(w4.w,x4.w,aB); \
    aA=fdot2f(w5.x,x5.x,aA); aB=fdot2f(w5.y,x5.y,aB); aA=fdot2f(w5.z,x5.z,aA); aB=fdot2f(w5.w,x5.w,aB); \
    dst = aA + aB; }
    float acc0,acc1,acc2,acc3,acc4,acc5,acc6,acc7;
    K6_DOT(0,acc0) K6_DOT(1,acc1) K6_DOT(2,acc2) K6_DOT(3,acc3)
    K6_DOT(4,acc4) K6_DOT(5,acc5) K6_DOT(6,acc6) K6_DOT(7,acc7)
    // tree-reduce across the 8 dim-slices; thread (r,s) keeps batch s
    float k0v = s0b? acc1:acc0, k0s = s0b? acc0:acc1;
    float k1v = s0b? acc3:acc2, k1s = s0b? acc2:acc3;
    float k2v = s0b? acc5:acc4, k2s = s0b? acc4:acc5;
    float k3v = s0b? acc7:acc6, k3s = s0b? acc6:acc7;
    k0v += __shfl_xor(k0s,1); k1v += __shfl_xor(k1s,1);
    k2v += __shfl_xor(k2s,1); k3v += __shfl_xor(k3s,1);
    float m0v = s1b? k1v:k0v, m0s = s1b? k0v:k1v;
    float m1v = s1b? k3v:k2v, m1s = s1b? k2v:k3v;
    m0v += __shfl_xor(m0s,2); m1v += __shfl_xor(m1s,2);
    float f0 = s2b? m1v:m0v, f0s = s2b? m0v:m1v;
    f0 += __shfl_xor(f0s,4);
    float xg_nxt = (t+1<S)? __half2float(xgc[((size_t)(t+1)*CG + grow)*8 + s]) : 0.f;
    gsum[r*9+s] = f0 + xg_cur;
    __syncthreads();
    int par = t & 1;
    u32 target = (u32)(t>>1) + 1u;
    if (tid < 128){
      int b = tid >> 4, mm = tid & 15;
      float gi=gsum[mm*9+b], gf=gsum[(16+mm)*9+b], gg=gsum[(32+mm)*9+b], go=gsum[(48+mm)*9+b];
      c_reg = sigf(gf)*c_reg + sigf(gi)*tanhfast(gg);
      float h = sigf(go)*tanhfast(c_reg);
      float h1 = __shfl_down(h, 1);
      if (!(mm & 1)){
        u32 pk = packh2(h, h1);
        int k = p*8 + (mm>>1);
        chs[((size_t)b*S + t)*192 + k] = pk;
        if (t+1 < S)
          __hip_atomic_store(&slots[(size_t)par*1536 + b*192 + k], ((u64)target<<32)|(u64)pk,
                             __ATOMIC_RELAXED, __HIP_MEMORY_SCOPE_AGENT);
      }
    } else if (t+1 < S){
      int base = (tid-128)*4;
#pragma unroll
      for (int q=0;q<4;q++){
        int i = base + q;
        u64 v;
        do { v = __hip_atomic_load(&slots[(size_t)par*1536 + i], __ATOMIC_RELAXED, __HIP_MEMORY_SCOPE_AGENT); }
        while ((u32)(v>>32) != target);
        h2[i] = (u32)v;
      }
    }
    xg_cur = xg_nxt;
    __syncthreads();
  }
}

// ---------------- K7a: sa source projection s_sa = c_hs @ saW1[:, :H3].T ----------------
// grid B*40 (v-tile 4), 384 threads
__global__ void k7a_sproj(float* __restrict__ ws, u32* __restrict__ wsu)
{
  int b = blockIdx.x/40; int v0 = (blockIdx.x%40)*4;
  const __half* chs = (const __half*)(wsu + CHS16);
  const float* wT = ws + SAT_S;
  __shared__ float xr[4][H3];
  int tid = threadIdx.x;
  for (int i=tid;i<4*H3;i+=384){ int r=i/H3, k=i%H3; xr[r][k] = __half2float(chs[(size_t)(b*S+v0+r)*H3 + k]); }
  __syncthreads();
  float acc[4] = {0.f,0.f,0.f,0.f};
  for (int k=0;k<H3;k++){
    float wv = wT[(size_t)k*H3 + tid];
#pragma unroll
    for (int r=0;r<4;r++) acc[r] = fmaf(xr[r][k], wv, acc[r]);
  }
#pragma unroll
  for (int r=0;r<4;r++) ws[S_SA + (size_t)(b*S+v0+r)*H3 + tid] = acc[r];
}

// ---------------- K7b: sa attention at the single needed row (lengths-1) ----------------
// grid B, 384 threads (6 waves)
__global__ void k7b_sa(float* __restrict__ ws, u32* __restrict__ wsu,
    const int* __restrict__ lengths, const float* __restrict__ sab1, const float* __restrict__ saw2)
{
  int b = blockIdx.x;
  int len = lengths[b]; int tr = len-1;
  const __half* chs = (const __half*)(wsu + CHS16);
  __shared__ float tv[H3]; __shared__ float chr[H3]; __shared__ float sc[S]; __shared__ float wg[S];
  int tid = threadIdx.x, wid = tid>>6, lane = tid&63;
  chr[tid] = __half2float(chs[(size_t)(b*S+tr)*H3 + tid]);
  __syncthreads();
  float acc = sab1[tid];
  for (int k=0;k<H3;k++) acc = fmaf(chr[k], ws[SAT_T + (size_t)k*H3 + tid], acc);
  tv[tid] = acc;
  __syncthreads();
  for (int v=wid; v<S; v+=6){
    const float* sr = ws + S_SA + (size_t)(b*S+v)*H3;
    float p = 0.f;
#pragma unroll
    for (int q=0;q<6;q++){
      int d = lane + 64*q;
      p = fmaf(tanhfast(tv[d] + sr[d]), saw2[d], p);
    }
    p = wred_sum(p);
    if (lane==0) sc[v] = p;
  }
  __syncthreads();
  if (tid < 64){
    float m0 = (lane<len)? sc[lane]:0.f;
    float m1 = (lane+64<len)? sc[lane+64]:0.f;
    float m2 = (lane<32)? ((lane+128<len)? sc[lane+128]:0.f) : -1e30f;
    float m = wred_max(fmaxf(fmaxf(m0,m1),m2));
    float e0=__expf(m0-m), e1=__expf(m1-m), e2=(lane<32)?__expf(m2-m):0.f;
    float inv = 1.f / wred_sum(e0+e1+e2);
    wg[lane]=e0*inv; wg[lane+64]=e1*inv; if (lane<32) wg[128+lane]=e2*inv;
  }
  __syncthreads();
  float o = 0.f;
  for (int v=0; v<S; v++) o = fmaf(wg[v], __half2float(chs[(size_t)(b*S+v)*H3 + tid]), o);
  ws[C_OUT + (size_t)b*H3 + tid] = o;
}

// ---------------- K8: final MLP ----------------
// grid B, 128 threads
__global__ void k8_mlp(float* __restrict__ ws, float* __restrict__ dout,
    const float* __restrict__ fc1W, const float* __restrict__ fc1b,
    const float* __restrict__ fc2W, const float* __restrict__ fc2b)
{
  int b = blockIdx.x, tid = threadIdx.x;
  __shared__ float feat[5*H]; __shared__ float r1[H];
  for (int i=tid;i<5*H;i+=128){
    float val;
    if (i < H3) val = ws[C_OUT + (size_t)b*H3 + i];
    else if (i < H3+H) val = ws[VCOMP + b*H + (i-H3)];
    else val = ws[ACOMP + b*H + (i-H3-H)];
    feat[i] = val;
  }
  __syncthreads();
  float acc = fc1b[tid];
  for (int k=0;k<5*H;k++) acc = fmaf(feat[k], fc1W[(size_t)tid*5*H + k], acc);
  r1[tid] = fmaxf(acc, 0.f) * fc2W[tid];
  __syncthreads();
  if (tid < 64){
    float p = r1[tid] + r1[tid+64];
    p = wred_sum(p);
    if (tid==0) dout[b] = p + fc2b[0];
  }
}

// ---------------- launch ----------------
extern "C" void kernel_launch(void* const* d_in, const int* in_sizes, int n_in,
                              void* d_out, int out_size, void* d_ws, size_t ws_size,
                              hipStream_t stream) {
  const float* xw = (const float*)d_in[0];
  const float* xv = (const float*)d_in[1];
  const float* xa = (const float*)d_in[2];
  const int* lengths = (const int*)d_in[3];
  const float* wWih=(const float*)d_in[4], *wWhh=(const float*)d_in[5], *wbih=(const float*)d_in[6], *wbhh=(const float*)d_in[7];
  const float* vWih=(const float*)d_in[8], *vWhh=(const float*)d_in[9], *vbih=(const float*)d_in[10], *vbhh=(const float*)d_in[11];
  const float* aWih=(const float*)d_in[12], *aWhh=(const float*)d_in[13], *abih=(const float*)d_in[14], *abhh=(const float*)d_in[15];
  const float* cWih=(const float*)d_in[16], *cWhh=(const float*)d_in[17], *cbih=(const float*)d_in[18], *cbhh=(const float*)d_in[19];
  const float* vwW1=(const float*)d_in[20], *vwb1=(const float*)d_in[21], *vww2=(const float*)d_in[22];
  const float* awW1=(const float*)d_in[23], *awb1=(const float*)d_in[24], *aww2=(const float*)d_in[25];
  const float* saW1=(const float*)d_in[26], *sab1=(const float*)d_in[27], *saw2=(const float*)d_in[28];
  const float* mpw=(const float*)d_in[29], *mpb=(const float*)d_in[30];
  const float* fc1W=(const float*)d_in[31], *fc1b=(const float*)d_in[32];
  const float* fc2W=(const float*)d_in[33], *fc2b=(const float*)d_in[34];
  float* ws = (float*)d_ws;
  u32* wsu = (u32*)d_ws;
  float* dout = (float*)d_out;

  hipLaunchKernelGGL(k0_prep, dim3((PREP_TOT+255)/256), dim3(256), 0, stream,
      ws, wsu, wWih,wbih,wbhh, vWih,vbih,vbhh, aWih,abih,abhh,
      cWih,cWhh,cbih,cbhh, vwW1, awW1, saW1);
  hipLaunchKernelGGL(k1_xg, dim3(480), dim3(256), 0, stream, ws, xw, xv, xa);
  hipLaunchKernelGGL(k2_lstm, dim3(24), dim3(1024), 0, stream, ws, wWhh, vWhh, aWhh);
  hipLaunchKernelGGL(k3a_proj, dim3(640), dim3(128), 0, stream, ws, vwb1, awb1);
  hipLaunchKernelGGL(k3b_attn, dim3(640), dim3(256), 0, stream, ws, dout, lengths, vww2, aww2);
  hipLaunchKernelGGL(k4_soft, dim3(16), dim3(256), 0, stream, ws, dout, mpw, mpb);
  hipLaunchKernelGGL(k5_xgc, dim3(B*40), dim3(512), 0, stream, ws, wsu);
  hipLaunchKernelGGL(k6_clstm, dim3(24), dim3(512), 0, stream, ws, wsu);
  hipLaunchKernelGGL(k7a_sproj, dim3(B*40), dim3(384), 0, stream, ws, wsu);
  hipLaunchKernelGGL(k7b_sa, dim3(B), dim3(384), 0, stream, ws, wsu, lengths, sab1, saw2);
  hipLaunchKernelGGL(k8_mlp, dim3(B), dim3(128), 0, stream, ws, dout, fc1W, fc1b, fc2W, fc2b);
}

// Round 5
// 958.405 us; speedup vs baseline: 1.2846x; 1.2846x over previous
//
#include <hip/hip_runtime.h>
#include <hip/hip_fp16.h>

typedef unsigned int u32;
typedef unsigned long long u64;

// ---------------- problem sizes ----------------
#define B 8
#define S 160
#define H 128
#define H3 384
#define G4 512
#define CG 1536
#define WIN 300
#define VIN 35
#define AIN 74

// ---------------- workspace layout (float-word offsets) ----------------
#define XG_W   0
#define XG_V   (XG_W + B*S*G4)
#define XG_A   (XG_V + B*S*G4)
#define HS_W   (XG_A + B*S*G4)
#define HS_V   (HS_W + B*S*H)
#define HS_A   (HS_V + B*S*H)
#define S_VW   (HS_A + B*S*H)
#define T_VW   (S_VW + B*S*H)
#define S_AW   (T_VW + B*S*H)
#define T_AW   (S_AW + B*S*H)
#define C_X    (T_AW + B*S*H)
#define S_SA   (C_X + B*S*H3)
#define WIHT_W (S_SA + B*S*H3)
#define WIHT_V (WIHT_W + WIN*G4)
#define WIHT_A (WIHT_V + VIN*G4)
#define WIHT_C (WIHT_A + AIN*G4)
#define WHHT_W (WIHT_C + H3*CG)
#define WHHT_V (WHHT_W + H*G4)
#define WHHT_A (WHHT_V + H*G4)
#define SAT_S  (WHHT_A + H*G4)
#define SAT_T  (SAT_S + H3*H3)
#define VW_ST  (SAT_T + H3*H3)
#define VW_TT  (VW_ST + H*H)
#define AW_ST  (VW_TT + H*H)
#define AW_TT  (AW_ST + H*H)
#define BSUM_W (AW_TT + H*H)
#define BSUM_V (BSUM_W + G4)
#define BSUM_A (BSUM_V + G4)
#define BSUM_C (BSUM_A + G4)
#define VCOMP  (BSUM_C + CG)
#define ACOMP  (VCOMP + B*H)
#define C_OUT  (ACOMP + B*H)
// u32 regions
#define XGC16  (C_OUT + B*H3)
// XGC16: f16 [b][t][gate]  (B*S*CG halves)
#define WRES   (XGC16 + B*S*CG/2)
// WRES: u32 idx = (((sl*48 + i)*256 + t)*4 + q) ; 48 uint4 per thread, coalesced
#define CHS16  (WRES + CG*H3/2)
// CHS16: u32 [b][t][192]  (c_hs f16 pairs)
#define H_X    (CHS16 + B*S*H3/2)
// H_X: u64 slots [par][b][192] = 2*8*192 u64 (seq<<32 | h-pair), poison-safe monotone seq

// ---------------- output layout ----------------
#define O_VATT  8
#define O_VSOFT (8 + B*S*S)
#define O_AATT  (O_VSOFT + B*S)
#define O_ASOFT (O_AATT + B*S*S)

// repetition macros (named registers: block shape sets the VGPR budget —
// 256-thread blocks = 1 wave/SIMD = 256 VGPRs; 512-thread = cap 128)
#define REP32(M) M(0)M(1)M(2)M(3)M(4)M(5)M(6)M(7)M(8)M(9)M(10)M(11)M(12)M(13)M(14)M(15)M(16)M(17)M(18)M(19)M(20)M(21)M(22)M(23)M(24)M(25)M(26)M(27)M(28)M(29)M(30)M(31)
#define REP48(M) REP32(M) M(32)M(33)M(34)M(35)M(36)M(37)M(38)M(39)M(40)M(41)M(42)M(43)M(44)M(45)M(46)M(47)

// ---------------- helpers ----------------
__device__ __forceinline__ float sigf(float x){ return 1.f/(1.f+__expf(-x)); }
__device__ __forceinline__ float tanhfast(float x){ float e=__expf(2.f*x); return 1.f - 2.f/(e+1.f); }
__device__ __forceinline__ float wred_sum(float x){
#pragma unroll
  for (int o=32;o;o>>=1) x += __shfl_xor(x,o);
  return x;
}
__device__ __forceinline__ float wred_max(float x){
#pragma unroll
  for (int o=32;o;o>>=1) x = fmaxf(x,__shfl_xor(x,o));
  return x;
}
__device__ __forceinline__ u32 packh2(float lo, float hi){
  __half a=__float2half_rn(lo), b=__float2half_rn(hi);
  return ((u32)__half_as_ushort(b)<<16) | (u32)__half_as_ushort(a);
}

typedef _Float16 h2v __attribute__((ext_vector_type(2)));
#if defined(__has_builtin)
#if __has_builtin(__builtin_amdgcn_fdot2)
#define HAVE_FDOT2 1
#endif
#endif
__device__ __forceinline__ float fdot2f(u32 w, u32 h, float acc){
#ifdef HAVE_FDOT2
  return __builtin_amdgcn_fdot2(__builtin_bit_cast(h2v,w), __builtin_bit_cast(h2v,h), acc, false);
#else
  h2v a=__builtin_bit_cast(h2v,w), b=__builtin_bit_cast(h2v,h);
  return acc + (float)a.x*(float)b.x + (float)a.y*(float)b.y;
#endif
}

// ---------------- K0: prep (transposes, bias sums, f16 packs) ----------------
#define PREP_TOT (3*G4 + CG + WIN*G4 + VIN*G4 + AIN*G4 + H3*CG + 3*H*G4 + 2*H3*H3 + 4*H*H + CG*H3/2)
__global__ void k0_prep(float* __restrict__ ws, u32* __restrict__ wsu,
    const float* __restrict__ wWih, const float* __restrict__ wWhh, const float* __restrict__ wbih, const float* __restrict__ wbhh,
    const float* __restrict__ vWih, const float* __restrict__ vWhh, const float* __restrict__ vbih, const float* __restrict__ vbhh,
    const float* __restrict__ aWih, const float* __restrict__ aWhh, const float* __restrict__ abih, const float* __restrict__ abhh,
    const float* __restrict__ cWih, const float* __restrict__ cWhh, const float* __restrict__ cbih, const float* __restrict__ cbhh,
    const float* __restrict__ vwW1, const float* __restrict__ awW1, const float* __restrict__ saW1)
{
  int idx = blockIdx.x*256 + threadIdx.x;
  if (idx >= PREP_TOT) return;
  if (idx < G4){ ws[BSUM_W+idx]=wbih[idx]+wbhh[idx]; return; } idx -= G4;
  if (idx < G4){ ws[BSUM_V+idx]=vbih[idx]+vbhh[idx]; return; } idx -= G4;
  if (idx < G4){ ws[BSUM_A+idx]=abih[idx]+abhh[idx]; return; } idx -= G4;
  if (idx < CG){ ws[BSUM_C+idx]=cbih[idx]+cbhh[idx]; return; } idx -= CG;
  if (idx < WIN*G4){ int k=idx/G4,g=idx%G4; ws[WIHT_W+idx]=wWih[g*WIN+k]; return; } idx -= WIN*G4;
  if (idx < VIN*G4){ int k=idx/G4,g=idx%G4; ws[WIHT_V+idx]=vWih[g*VIN+k]; return; } idx -= VIN*G4;
  if (idx < AIN*G4){ int k=idx/G4,g=idx%G4; ws[WIHT_A+idx]=aWih[g*AIN+k]; return; } idx -= AIN*G4;
  if (idx < H3*CG){ int k=idx/CG,g=idx%CG; ws[WIHT_C+idx]=cWih[g*H3+k]; return; } idx -= H3*CG;
  if (idx < H*G4){ int q=idx&3, r=idx>>2, g=r&511, k4=r>>9; ws[WHHT_W+idx]=wWhh[g*H + 4*k4+q]; return; } idx -= H*G4;
  if (idx < H*G4){ int q=idx&3, r=idx>>2, g=r&511, k4=r>>9; ws[WHHT_V+idx]=vWhh[g*H + 4*k4+q]; return; } idx -= H*G4;
  if (idx < H*G4){ int q=idx&3, r=idx>>2, g=r&511, k4=r>>9; ws[WHHT_A+idx]=aWhh[g*H + 4*k4+q]; return; } idx -= H*G4;
  if (idx < H3*H3){ int k=idx/H3,d=idx%H3; ws[SAT_S+idx]=saW1[d*(2*H3)+k]; return; } idx -= H3*H3;
  if (idx < H3*H3){ int k=idx/H3,d=idx%H3; ws[SAT_T+idx]=saW1[d*(2*H3)+H3+k]; return; } idx -= H3*H3;
  if (idx < H*H){ int k=idx/H,d=idx%H; ws[VW_ST+idx]=vwW1[d*(2*H)+k]; return; } idx -= H*H;
  if (idx < H*H){ int k=idx/H,d=idx%H; ws[VW_TT+idx]=vwW1[d*(2*H)+H+k]; return; } idx -= H*H;
  if (idx < H*H){ int k=idx/H,d=idx%H; ws[AW_ST+idx]=awW1[d*(2*H)+k]; return; } idx -= H*H;
  if (idx < H*H){ int k=idx/H,d=idx%H; ws[AW_TT+idx]=awW1[d*(2*H)+H+k]; return; } idx -= H*H;
  // WRES: c_Whh -> f16x2, k6 per-thread layout, lane-coalesced residency loads
  {
    int q = idx & 3; int r = idx >> 2;
    int t = r & 255; int r2 = r >> 8;
    int i = r2 % 48; int sl = r2 / 48;
    int j = t >> 6, ul = t & 63;
    int row = j*H3 + sl*64 + ul;
    int k2 = i*4 + q;
    wsu[WRES+idx] = packh2(cWhh[(size_t)row*H3 + 2*k2], cWhh[(size_t)row*H3 + 2*k2 + 1]);
  }
}

// ---------------- K1: input projections xg for w/v/a LSTMs ----------------
// grid: 3 * B * (S/8) = 480 blocks, 256 threads
__global__ void k1_xg(float* __restrict__ ws,
    const float* __restrict__ xw, const float* __restrict__ xv, const float* __restrict__ xa)
{
  int bid = blockIdx.x;
  int lstm = bid/160; int rem = bid%160; int b = rem/20; int s0 = (rem%20)*8;
  int in_dim; const float* x; const float* wT; const float* bs; float* xg;
  if (lstm==0){ in_dim=WIN; x=xw; wT=ws+WIHT_W; bs=ws+BSUM_W; xg=ws+XG_W; }
  else if (lstm==1){ in_dim=VIN; x=xv; wT=ws+WIHT_V; bs=ws+BSUM_V; xg=ws+XG_V; }
  else { in_dim=AIN; x=xa; wT=ws+WIHT_A; bs=ws+BSUM_A; xg=ws+XG_A; }
  __shared__ float xt[8][WIN];
  int tid = threadIdx.x;
  for (int i=tid; i<8*in_dim; i+=256){ int r=i/in_dim, k=i%in_dim; xt[r][k] = x[((size_t)(b*S+s0+r))*in_dim + k]; }
  __syncthreads();
  float acc0[8], acc1[8];
  float b0 = bs[tid], b1 = bs[tid+256];
#pragma unroll
  for (int r=0;r<8;r++){ acc0[r]=b0; acc1[r]=b1; }
  for (int k=0;k<in_dim;k++){
    float w0 = wT[k*G4 + tid], w1 = wT[k*G4 + 256 + tid];
#pragma unroll
    for (int r=0;r<8;r++){ float xx = xt[r][k]; acc0[r] = fmaf(xx,w0,acc0[r]); acc1[r] = fmaf(xx,w1,acc1[r]); }
  }
#pragma unroll
  for (int r=0;r<8;r++){
    size_t ro = (size_t)(b*S+s0+r)*G4;
    xg[ro + tid] = acc0[r];
    xg[ro + 256 + tid] = acc1[r];
  }
}

// ---------------- K2: w/v/a LSTM recurrences (one block per lstm,batch) ----------------
// grid 24 blocks, 512 threads; Whh in 32 named float4 (round-3 best-known version).
__global__ __launch_bounds__(512,1) void k2_lstm(float* __restrict__ ws)
{
  int lstm = blockIdx.x >> 3, b = blockIdx.x & 7;
  const float* xg; const float* whhT; float* hs; float* cx = nullptr;
  if (lstm==0){ xg=ws+XG_W; whhT=ws+WHHT_W; hs=ws+HS_W; cx=ws+C_X; }
  else if (lstm==1){ xg=ws+XG_V; whhT=ws+WHHT_V; hs=ws+HS_V; }
  else { xg=ws+XG_A; whhT=ws+WHHT_A; hs=ws+HS_A; }
  int g = threadIdx.x;
  const float4* wb = ((const float4*)whhT) + g;
#define K2_LD(i) float4 w##i = wb[(i)*512];
  REP32(K2_LD)
  __shared__ __align__(16) float hbuf[H];
  __shared__ float gsum[G4];
  float c_reg = 0.f;
  if (g < H) hbuf[g] = 0.f;
  const float* xgb = xg + (size_t)b*S*G4;
  float* hsb = hs + (size_t)b*S*H;
  float* cxb = cx ? cx + (size_t)b*S*H3 : nullptr;
  float xg_cur = xgb[g];
  __syncthreads();
  const float4* h4p = (const float4*)hbuf;
  for (int t=0;t<S;t++){
    float acc = xg_cur;
    float xg_nxt = (t+1<S) ? xgb[(size_t)(t+1)*G4 + g] : 0.f;
#define K2_FMA(i) { float4 h4 = h4p[i]; acc = fmaf(w##i.x,h4.x,acc); acc = fmaf(w##i.y,h4.y,acc); acc = fmaf(w##i.z,h4.z,acc); acc = fmaf(w##i.w,h4.w,acc); }
    REP32(K2_FMA)
    gsum[g] = acc;
    xg_cur = xg_nxt;
    __syncthreads();
    if (g < H){
      float gi=gsum[g], gf=gsum[H+g], gg=gsum[2*H+g], go=gsum[3*H+g];
      c_reg = sigf(gf)*c_reg + sigf(gi)*tanhfast(gg);
      float h = sigf(go)*tanhfast(c_reg);
      hbuf[g] = h;
      hsb[(size_t)t*H + g] = h;
      if (cxb) cxb[(size_t)t*H3 + g] = h;
    }
    __syncthreads();
  }
}

// ---------------- K3a: attention projections (s/t for vw and aw) ----------------
// grid 4*B*(S/8)=640, 128 threads
__global__ void k3a_proj(float* __restrict__ ws, const float* __restrict__ vwb1, const float* __restrict__ awb1)
{
  int bid = blockIdx.x;
  int p = bid/160; int rem = bid%160; int b = rem/20; int s0 = (rem%20)*8;
  const float* src; const float* wT; const float* bias=nullptr; float* dst;
  if (p==0){ src=ws+HS_V; wT=ws+VW_ST; dst=ws+S_VW; }
  else if (p==1){ src=ws+HS_W; wT=ws+VW_TT; bias=vwb1; dst=ws+T_VW; }
  else if (p==2){ src=ws+HS_A; wT=ws+AW_ST; dst=ws+S_AW; }
  else { src=ws+HS_W; wT=ws+AW_TT; bias=awb1; dst=ws+T_AW; }
  __shared__ float xr[8][H];
  int tid = threadIdx.x;
  for (int i=tid;i<8*H;i+=128){ int r=i>>7, k=i&127; xr[r][k] = src[(size_t)(b*S+s0+r)*H + k]; }
  __syncthreads();
  float acc[8];
  float bv = bias ? bias[tid] : 0.f;
#pragma unroll
  for (int r=0;r<8;r++) acc[r]=bv;
  for (int k=0;k<H;k++){
    float wv = wT[k*H + tid];
#pragma unroll
    for (int r=0;r<8;r++) acc[r] = fmaf(xr[r][k], wv, acc[r]);
  }
#pragma unroll
  for (int r=0;r<8;r++) dst[(size_t)(b*S+s0+r)*H + tid] = acc[r];
}

// ---------------- K3b: vw/aw cross-attention (scores, softmax, out) ----------------
// grid 2*B*S/4 = 640 blocks of 256 (wave per (A,b,w) row)
__global__ void k3b_attn(float* __restrict__ ws, float* __restrict__ dout,
    const int* __restrict__ lengths, const float* __restrict__ vww2, const float* __restrict__ aww2)
{
  int wid = threadIdx.x >> 6, lane = threadIdx.x & 63;
  int row = blockIdx.x*4 + wid;
  int A = row / (B*S); int rem = row % (B*S); int b = rem / S; int w = rem % S;
  const float* sp = ws + (A? S_AW : S_VW) + (size_t)(b*S)*H;
  const float* tp = ws + (A? T_AW : T_VW) + (size_t)(b*S + w)*H;
  const float* w2 = A? aww2 : vww2;
  const float* src = ws + (A? HS_A : HS_V) + (size_t)(b*S)*H;
  float* attw = dout + (A? O_AATT : O_VATT) + (size_t)b*S*S + (size_t)w*S;
  int len = lengths[b];
  __shared__ float sc[4][S];
  float2 t2 = ((const float2*)tp)[lane];
  float2 w22 = ((const float2*)w2)[lane];
  for (int v=0; v<S; v++){
    float2 s2 = ((const float2*)(sp + (size_t)v*H))[lane];
    float x0 = tanhfast(t2.x + s2.x), x1 = tanhfast(t2.y + s2.y);
    float p = wred_sum(x0*w22.x + x1*w22.y);
    if (lane==0) sc[wid][v] = p;
  }
  __syncthreads();
  float m0 = (lane      < len)? sc[wid][lane]     : 0.f;
  float m1 = (lane+64   < len)? sc[wid][lane+64]  : 0.f;
  float m2 = (lane<32) ? ((lane+128 < len)? sc[wid][lane+128] : 0.f) : -1e30f;
  float m = wred_max(fmaxf(fmaxf(m0,m1),m2));
  float e0 = __expf(m0-m), e1 = __expf(m1-m), e2 = (lane<32)? __expf(m2-m) : 0.f;
  float inv = 1.f / wred_sum(e0+e1+e2);
  e0*=inv; e1*=inv; e2*=inv;
  sc[wid][lane] = e0; sc[wid][lane+64] = e1; if (lane<32) sc[wid][128+lane] = e2;
  attw[lane] = e0; attw[lane+64] = e1; if (lane<32) attw[128+lane] = e2;
  __syncthreads();
  float2 acc; acc.x=0.f; acc.y=0.f;
  for (int v=0; v<S; v++){
    float wg = sc[wid][v];
    float2 sv = ((const float2*)(src + (size_t)v*H))[lane];
    acc.x = fmaf(wg, sv.x, acc.x); acc.y = fmaf(wg, sv.y, acc.y);
  }
  float* cxr = ws + C_X + (size_t)(b*S + w)*H3 + (A? 2*H : H);
  ((float2*)cxr)[lane] = acc;
}

// ---------------- K4: soft attention (v and a) ----------------
// grid 16 (A*8+b), 256 threads
__global__ void k4_soft(float* __restrict__ ws, float* __restrict__ dout,
    const float* __restrict__ mpw, const float* __restrict__ mpb)
{
  int A = blockIdx.x >> 3, b = blockIdx.x & 7;
  const float* reps = ws + (A? HS_A : HS_V) + (size_t)(b*S)*H;
  float* softw = dout + (A? O_ASOFT : O_VSOFT) + b*S;
  float* comp = ws + (A? ACOMP : VCOMP) + b*H;
  __shared__ float sc[S]; __shared__ float wg[S];
  int wid = threadIdx.x >> 6, lane = threadIdx.x & 63;
  float bb = mpb[0];
  for (int s=wid; s<S; s+=4){
    float2 r2 = ((const float2*)(reps + (size_t)s*H))[lane];
    float2 m2 = ((const float2*)mpw)[lane];
    float p = wred_sum(r2.x*m2.x + r2.y*m2.y);
    if (lane==0) sc[s] = p + bb;
  }
  __syncthreads();
  if (threadIdx.x < 64){
    float m0 = sc[lane], m1 = sc[lane+64], m2 = (lane<32)? sc[lane+128] : -1e30f;
    float m = wred_max(fmaxf(fmaxf(m0,m1),m2));
    float e0=__expf(m0-m), e1=__expf(m1-m), e2=(lane<32)?__expf(m2-m):0.f;
    float inv = 1.f / wred_sum(e0+e1+e2);
    e0*=inv; e1*=inv; e2*=inv;
    wg[lane]=e0; wg[lane+64]=e1; if (lane<32) wg[128+lane]=e2;
    softw[lane]=e0; softw[lane+64]=e1; if (lane<32) softw[128+lane]=e2;
  }
  __syncthreads();
  if (threadIdx.x < H){
    float acc=0.f;
    for (int s=0;s<S;s++) acc = fmaf(wg[s], reps[(size_t)s*H + threadIdx.x], acc);
    comp[threadIdx.x] = acc;
  }
}

// ---------------- K5: c-LSTM input projection -> xgc [b][t][gate] f16 ----------------
// grid B*40 (s-tile 4), 512 threads
__global__ void k5_xgc(float* __restrict__ ws, u32* __restrict__ wsu)
{
  int b = blockIdx.x/40; int s0 = (blockIdx.x%40)*4;
  const float* cxb = ws + C_X + (size_t)(b*S+s0)*H3;
  const float* wT = ws + WIHT_C;
  const float* bs = ws + BSUM_C;
  __half* xgc = (__half*)(wsu + XGC16);
  __shared__ float xr[4][H3];
  int tid = threadIdx.x;
  for (int i=tid;i<4*H3;i+=512){ int r=i/H3, k=i%H3; xr[r][k]=cxb[(size_t)r*H3+k]; }
  __syncthreads();
  float acc[4][3];
  float b0=bs[tid], b1=bs[tid+512], b2=bs[tid+1024];
#pragma unroll
  for (int r=0;r<4;r++){ acc[r][0]=b0; acc[r][1]=b1; acc[r][2]=b2; }
  for (int k=0;k<H3;k++){
    float w0=wT[(size_t)k*CG+tid], w1=wT[(size_t)k*CG+512+tid], w2v=wT[(size_t)k*CG+1024+tid];
#pragma unroll
    for (int r=0;r<4;r++){
      float xx = xr[r][k];
      acc[r][0]=fmaf(xx,w0,acc[r][0]); acc[r][1]=fmaf(xx,w1,acc[r][1]); acc[r][2]=fmaf(xx,w2v,acc[r][2]);
    }
  }
#pragma unroll
  for (int r=0;r<4;r++){
    size_t ro = (size_t)(b*S + s0+r)*CG;
    xgc[ro + tid]        = __float2half_rn(acc[r][0]);
    xgc[ro + 512 + tid]  = __float2half_rn(acc[r][1]);
    xgc[ro + 1024 + tid] = __float2half_rn(acc[r][2]);
  }
}

// ---------------- K6: c-LSTM recurrence ----------------
// 48 blocks = sl*8 + b (6 slices per batch; same-XCD under mod-8 round robin).
// 256 threads (4 waves = 1/SIMD -> 256-VGPR budget): thread (j,ul) owns gate row
// j*H3 + sl*64 + ul with FULL 384-dim f16 weights = 48 named uint4 (192 VGPR).
// Dot: 48 broadcast LDS reads (conflict-free) + 192 fdot2.
// Exchange: wave0 computes h for this block's 64 cells, publishes 32 seq-tagged
// u64; 160 poller threads spin on ONE remote slot each. Monotone seq + parity
// double-buffer => no resets, re-poison-safe (0xAAAAAAAA never matches a target).
__global__ __launch_bounds__(256,1) void k6_clstm(float* __restrict__ ws, u32* __restrict__ wsu)
{
  int b = blockIdx.x & 7, sl = blockIdx.x >> 3;
  int tid = threadIdx.x, j = tid>>6, ul = tid&63;
  const __half* xgb = ((const __half*)(wsu + XGC16)) + (size_t)b*S*CG;
  u32* chsb = wsu + CHS16 + (size_t)b*S*(H3/2);
  u64* slots = (u64*)(wsu + H_X);   // [par][b][192]
  const uint4* wb = ((const uint4*)(wsu + WRES)) + (size_t)sl*48*256 + tid;
#define K6_LD(i) uint4 w##i = wb[(i)*256];
  REP48(K6_LD)
  __shared__ __align__(16) u32 h2[H3/2];
  __shared__ float gsum[256];
  float c_reg = 0.f;
  if (tid < H3/2) h2[tid] = 0u;
  int row = j*H3 + sl*64 + ul;
  float xg_cur = __half2float(xgb[row]);
  __syncthreads();
  const uint4* h2q = (const uint4*)h2;
  for (int t=0;t<S;t++){
    float acc = xg_cur;
#define K6_FD(i) { uint4 hh = h2q[i]; acc = fdot2f(w##i.x,hh.x,acc); acc = fdot2f(w##i.y,hh.y,acc); acc = fdot2f(w##i.z,hh.z,acc); acc = fdot2f(w##i.w,hh.w,acc); }
    REP48(K6_FD)
    float xg_nxt = (t+1<S)? __half2float(xgb[(size_t)(t+1)*CG + row]) : 0.f;
    gsum[tid] = acc;
    xg_cur = xg_nxt;
    __syncthreads();
    int par = t & 1;
    u32 target = (u32)(t>>1) + 1u;
    u64* sb = slots + ((size_t)par*8 + b)*192;
    if (tid < 64){
      float gi=gsum[tid], gf=gsum[64+tid], gg=gsum[128+tid], go=gsum[192+tid];
      c_reg = sigf(gf)*c_reg + sigf(gi)*tanhfast(gg);
      float h = sigf(go)*tanhfast(c_reg);
      float h1 = __shfl_down(h, 1);
      if (!(tid & 1)){
        u32 pk = packh2(h, h1);
        int p = sl*32 + (tid>>1);
        h2[p] = pk;
        chsb[(size_t)t*(H3/2) + p] = pk;
        if (t+1 < S)
          __hip_atomic_store(&sb[p], ((u64)target<<32) | (u64)pk,
                             __ATOMIC_RELAXED, __HIP_MEMORY_SCOPE_AGENT);
      }
    } else if (t+1 < S){
      int i = tid - 64;
      if (i < 160){
        int pi = i >> 5;
        int psl = sl + 1 + pi; if (psl >= 6) psl -= 6;
        int p = psl*32 + (i & 31);
        u64 v;
        do { v = __hip_atomic_load(&sb[p], __ATOMIC_RELAXED, __HIP_MEMORY_SCOPE_AGENT); }
        while ((u32)(v>>32) != target);
        h2[p] = (u32)v;
      }
    }
    __syncthreads();
  }
}

// ---------------- K7a: sa source projection s_sa = c_hs @ saW1[:, :H3].T ----------------
// grid B*40 (v-tile 4), 384 threads
__global__ void k7a_sproj(float* __restrict__ ws, u32* __restrict__ wsu)
{
  int b = blockIdx.x/40; int v0 = (blockIdx.x%40)*4;
  const __half* chs = (const __half*)(wsu + CHS16);
  const float* wT = ws + SAT_S;
  __shared__ float xr[4][H3];
  int tid = threadIdx.x;
  for (int i=tid;i<4*H3;i+=384){ int r=i/H3, k=i%H3; xr[r][k] = __half2float(chs[(size_t)(b*S+v0+r)*H3 + k]); }
  __syncthreads();
  float acc[4] = {0.f,0.f,0.f,0.f};
  for (int k=0;k<H3;k++){
    float wv = wT[(size_t)k*H3 + tid];
#pragma unroll
    for (int r=0;r<4;r++) acc[r] = fmaf(xr[r][k], wv, acc[r]);
  }
#pragma unroll
  for (int r=0;r<4;r++) ws[S_SA + (size_t)(b*S+v0+r)*H3 + tid] = acc[r];
}

// ---------------- K7b: sa attention at the single needed row (lengths-1) ----------------
// grid B, 384 threads (6 waves)
__global__ void k7b_sa(float* __restrict__ ws, u32* __restrict__ wsu,
    const int* __restrict__ lengths, const float* __restrict__ sab1, const float* __restrict__ saw2)
{
  int b = blockIdx.x;
  int len = lengths[b]; int tr = len-1;
  const __half* chs = (const __half*)(wsu + CHS16);
  __shared__ float tv[H3]; __shared__ float chr[H3]; __shared__ float sc[S]; __shared__ float wg[S];
  int tid = threadIdx.x, wid = tid>>6, lane = tid&63;
  chr[tid] = __half2float(chs[(size_t)(b*S+tr)*H3 + tid]);
  __syncthreads();
  float acc = sab1[tid];
  for (int k=0;k<H3;k++) acc = fmaf(chr[k], ws[SAT_T + (size_t)k*H3 + tid], acc);
  tv[tid] = acc;
  __syncthreads();
  for (int v=wid; v<S; v+=6){
    const float* sr = ws + S_SA + (size_t)(b*S+v)*H3;
    float p = 0.f;
#pragma unroll
    for (int q=0;q<6;q++){
      int d = lane + 64*q;
      p = fmaf(tanhfast(tv[d] + sr[d]), saw2[d], p);
    }
    p = wred_sum(p);
    if (lane==0) sc[v] = p;
  }
  __syncthreads();
  if (tid < 64){
    float m0 = (lane<len)? sc[lane]:0.f;
    float m1 = (lane+64<len)? sc[lane+64]:0.f;
    float m2 = (lane<32)? ((lane+128<len)? sc[lane+128]:0.f) : -1e30f;
    float m = wred_max(fmaxf(fmaxf(m0,m1),m2));
    float e0=__expf(m0-m), e1=__expf(m1-m), e2=(lane<32)?__expf(m2-m):0.f;
    float inv = 1.f / wred_sum(e0+e1+e2);
    wg[lane]=e0*inv; wg[lane+64]=e1*inv; if (lane<32) wg[128+lane]=e2*inv;
  }
  __syncthreads();
  float o = 0.f;
  for (int v=0; v<S; v++) o = fmaf(wg[v], __half2float(chs[(size_t)(b*S+v)*H3 + tid]), o);
  ws[C_OUT + (size_t)b*H3 + tid] = o;
}

// ---------------- K8: final MLP ----------------
// grid B, 128 threads
__global__ void k8_mlp(float* __restrict__ ws, float* __restrict__ dout,
    const float* __restrict__ fc1W, const float* __restrict__ fc1b,
    const float* __restrict__ fc2W, const float* __restrict__ fc2b)
{
  int b = blockIdx.x, tid = threadIdx.x;
  __shared__ float feat[5*H]; __shared__ float r1[H];
  for (int i=tid;i<5*H;i+=128){
    float val;
    if (i < H3) val = ws[C_OUT + (size_t)b*H3 + i];
    else if (i < H3+H) val = ws[VCOMP + b*H + (i-H3)];
    else val = ws[ACOMP + b*H + (i-H3-H)];
    feat[i] = val;
  }
  __syncthreads();
  float acc = fc1b[tid];
  for (int k=0;k<5*H;k++) acc = fmaf(feat[k], fc1W[(size_t)tid*5*H + k], acc);
  r1[tid] = fmaxf(acc, 0.f) * fc2W[tid];
  __syncthreads();
  if (tid < 64){
    float p = r1[tid] + r1[tid+64];
    p = wred_sum(p);
    if (tid==0) dout[b] = p + fc2b[0];
  }
}

// ---------------- launch ----------------
extern "C" void kernel_launch(void* const* d_in, const int* in_sizes, int n_in,
                              void* d_out, int out_size, void* d_ws, size_t ws_size,
                              hipStream_t stream) {
  const float* xw = (const float*)d_in[0];
  const float* xv = (const float*)d_in[1];
  const float* xa = (const float*)d_in[2];
  const int* lengths = (const int*)d_in[3];
  const float* wWih=(const float*)d_in[4], *wWhh=(const float*)d_in[5], *wbih=(const float*)d_in[6], *wbhh=(const float*)d_in[7];
  const float* vWih=(const float*)d_in[8], *vWhh=(const float*)d_in[9], *vbih=(const float*)d_in[10], *vbhh=(const float*)d_in[11];
  const float* aWih=(const float*)d_in[12], *aWhh=(const float*)d_in[13], *abih=(const float*)d_in[14], *abhh=(const float*)d_in[15];
  const float* cWih=(const float*)d_in[16], *cWhh=(const float*)d_in[17], *cbih=(const float*)d_in[18], *cbhh=(const float*)d_in[19];
  const float* vwW1=(const float*)d_in[20], *vwb1=(const float*)d_in[21], *vww2=(const float*)d_in[22];
  const float* awW1=(const float*)d_in[23], *awb1=(const float*)d_in[24], *aww2=(const float*)d_in[25];
  const float* saW1=(const float*)d_in[26], *sab1=(const float*)d_in[27], *saw2=(const float*)d_in[28];
  const float* mpw=(const float*)d_in[29], *mpb=(const float*)d_in[30];
  const float* fc1W=(const float*)d_in[31], *fc1b=(const float*)d_in[32];
  const float* fc2W=(const float*)d_in[33], *fc2b=(const float*)d_in[34];
  float* ws = (float*)d_ws;
  u32* wsu = (u32*)d_ws;
  float* dout = (float*)d_out;

  hipLaunchKernelGGL(k0_prep, dim3((PREP_TOT+255)/256), dim3(256), 0, stream,
      ws, wsu, wWih,wWhh,wbih,wbhh, vWih,vWhh,vbih,vbhh, aWih,aWhh,abih,abhh,
      cWih,cWhh,cbih,cbhh, vwW1, awW1, saW1);
  hipLaunchKernelGGL(k1_xg, dim3(480), dim3(256), 0, stream, ws, xw, xv, xa);
  hipLaunchKernelGGL(k2_lstm, dim3(24), dim3(512), 0, stream, ws);
  hipLaunchKernelGGL(k3a_proj, dim3(640), dim3(128), 0, stream, ws, vwb1, awb1);
  hipLaunchKernelGGL(k3b_attn, dim3(640), dim3(256), 0, stream, ws, dout, lengths, vww2, aww2);
  hipLaunchKernelGGL(k4_soft, dim3(16), dim3(256), 0, stream, ws, dout, mpw, mpb);
  hipLaunchKernelGGL(k5_xgc, dim3(B*40), dim3(512), 0, stream, ws, wsu);
  hipLaunchKernelGGL(k6_clstm, dim3(48), dim3(256), 0, stream, ws, wsu);
  hipLaunchKernelGGL(k7a_sproj, dim3(B*40), dim3(384), 0, stream, ws, wsu);
  hipLaunchKernelGGL(k7b_sa, dim3(B), dim3(384), 0, stream, ws, wsu, lengths, sab1, saw2);
  hipLaunchKernelGGL(k8_mlp, dim3(B), dim3(128), 0, stream, ws, dout, fc1W, fc1b, fc2W, fc2b);
}

// Round 7
// 922.396 us; speedup vs baseline: 1.3348x; 1.0390x over previous
//
#include <hip/hip_runtime.h>
#include <hip/hip_fp16.h>

typedef unsigned int u32;
typedef unsigned long long u64;

// ---------------- problem sizes ----------------
#define B 8
#define S 160
#define H 128
#define H3 384
#define G4 512
#define CG 1536
#define WIN 300
#define VIN 35
#define AIN 74

// ---------------- workspace layout (float-word offsets) ----------------
#define XG_W   0
#define XG_V   (XG_W + B*S*G4)
#define XG_A   (XG_V + B*S*G4)
#define HS_W   (XG_A + B*S*G4)
#define HS_V   (HS_W + B*S*H)
#define HS_A   (HS_V + B*S*H)
#define S_VW   (HS_A + B*S*H)
#define T_VW   (S_VW + B*S*H)
#define S_AW   (T_VW + B*S*H)
#define T_AW   (S_AW + B*S*H)
#define C_X    (T_AW + B*S*H)
#define S_SA   (C_X + B*S*H3)
#define WIHT_W (S_SA + B*S*H3)
#define WIHT_V (WIHT_W + WIN*G4)
#define WIHT_A (WIHT_V + VIN*G4)
#define WIHT_C (WIHT_A + AIN*G4)
#define WHHT_W (WIHT_C + H3*CG)
#define WHHT_V (WHHT_W + H*G4)
#define WHHT_A (WHHT_V + H*G4)
#define SAT_S  (WHHT_A + H*G4)
#define SAT_T  (SAT_S + H3*H3)
#define VW_ST  (SAT_T + H3*H3)
#define VW_TT  (VW_ST + H*H)
#define AW_ST  (VW_TT + H*H)
#define AW_TT  (AW_ST + H*H)
#define BSUM_W (AW_TT + H*H)
#define BSUM_V (BSUM_W + G4)
#define BSUM_A (BSUM_V + G4)
#define BSUM_C (BSUM_A + G4)
#define VCOMP  (BSUM_C + CG)
#define ACOMP  (VCOMP + B*H)
#define C_OUT  (ACOMP + B*H)
// u32 regions
#define XGC16  (C_OUT + B*H3)
// XGC16: f16 [b][t][gate]  (B*S*CG halves)
#define WRES   (XGC16 + B*S*CG/2)
// WRES: uint4 idx = (sl*48 + j)*256 + tid ; per-thread j = gate*12 + ii,
//       value pairs k2 = q*48 + ii*4 + q4 of row gate*H3 + sl*64 + (tid>>2)
#define CHS16  (WRES + CG*H3/2)
// CHS16: u32 [b][t][192]  (c_hs f16 pairs)
#define H_X    (CHS16 + B*S*H3/2)
// H_X: u64 slots [par][b][192] (seq<<32 | h-pair), poison-safe monotone seq

// ---------------- output layout ----------------
#define O_VATT  8
#define O_VSOFT (8 + B*S*S)
#define O_AATT  (O_VSOFT + B*S)
#define O_ASOFT (O_AATT + B*S*S)

// repetition macros (named registers: block shape sets the VGPR budget —
// 256-thread blocks = 1 wave/SIMD = 256 VGPRs)
#define REP32(M) M(0)M(1)M(2)M(3)M(4)M(5)M(6)M(7)M(8)M(9)M(10)M(11)M(12)M(13)M(14)M(15)M(16)M(17)M(18)M(19)M(20)M(21)M(22)M(23)M(24)M(25)M(26)M(27)M(28)M(29)M(30)M(31)
#define REP48(M) REP32(M) M(32)M(33)M(34)M(35)M(36)M(37)M(38)M(39)M(40)M(41)M(42)M(43)M(44)M(45)M(46)M(47)

// ---------------- helpers ----------------
__device__ __forceinline__ float sigf(float x){ return 1.f/(1.f+__expf(-x)); }
__device__ __forceinline__ float tanhfast(float x){ float e=__expf(2.f*x); return 1.f - 2.f/(e+1.f); }
__device__ __forceinline__ float wred_sum(float x){
#pragma unroll
  for (int o=32;o;o>>=1) x += __shfl_xor(x,o);
  return x;
}
__device__ __forceinline__ float wred_max(float x){
#pragma unroll
  for (int o=32;o;o>>=1) x = fmaxf(x,__shfl_xor(x,o));
  return x;
}
__device__ __forceinline__ u32 packh2(float lo, float hi){
  __half a=__float2half_rn(lo), b=__float2half_rn(hi);
  return ((u32)__half_as_ushort(b)<<16) | (u32)__half_as_ushort(a);
}

typedef _Float16 h2v __attribute__((ext_vector_type(2)));
#if defined(__has_builtin)
#if __has_builtin(__builtin_amdgcn_fdot2)
#define HAVE_FDOT2 1
#endif
#endif
__device__ __forceinline__ float fdot2f(u32 w, u32 h, float acc){
#ifdef HAVE_FDOT2
  return __builtin_amdgcn_fdot2(__builtin_bit_cast(h2v,w), __builtin_bit_cast(h2v,h), acc, false);
#else
  h2v a=__builtin_bit_cast(h2v,w), b=__builtin_bit_cast(h2v,h);
  return acc + (float)a.x*(float)b.x + (float)a.y*(float)b.y;
#endif
}

// ---------------- K0: prep (transposes, bias sums, f16 packs) ----------------
#define PREP_TOT (3*G4 + CG + WIN*G4 + VIN*G4 + AIN*G4 + H3*CG + 3*H*G4 + 2*H3*H3 + 4*H*H + CG*H3/2)
__global__ void k0_prep(float* __restrict__ ws, u32* __restrict__ wsu,
    const float* __restrict__ wWih, const float* __restrict__ wWhh, const float* __restrict__ wbih, const float* __restrict__ wbhh,
    const float* __restrict__ vWih, const float* __restrict__ vWhh, const float* __restrict__ vbih, const float* __restrict__ vbhh,
    const float* __restrict__ aWih, const float* __restrict__ aWhh, const float* __restrict__ abih, const float* __restrict__ abhh,
    const float* __restrict__ cWih, const float* __restrict__ cWhh, const float* __restrict__ cbih, const float* __restrict__ cbhh,
    const float* __restrict__ vwW1, const float* __restrict__ awW1, const float* __restrict__ saW1)
{
  int idx = blockIdx.x*256 + threadIdx.x;
  if (idx >= PREP_TOT) return;
  if (idx < G4){ ws[BSUM_W+idx]=wbih[idx]+wbhh[idx]; return; } idx -= G4;
  if (idx < G4){ ws[BSUM_V+idx]=vbih[idx]+vbhh[idx]; return; } idx -= G4;
  if (idx < G4){ ws[BSUM_A+idx]=abih[idx]+abhh[idx]; return; } idx -= G4;
  if (idx < CG){ ws[BSUM_C+idx]=cbih[idx]+cbhh[idx]; return; } idx -= CG;
  if (idx < WIN*G4){ int k=idx/G4,g=idx%G4; ws[WIHT_W+idx]=wWih[g*WIN+k]; return; } idx -= WIN*G4;
  if (idx < VIN*G4){ int k=idx/G4,g=idx%G4; ws[WIHT_V+idx]=vWih[g*VIN+k]; return; } idx -= VIN*G4;
  if (idx < AIN*G4){ int k=idx/G4,g=idx%G4; ws[WIHT_A+idx]=aWih[g*AIN+k]; return; } idx -= AIN*G4;
  if (idx < H3*CG){ int k=idx/CG,g=idx%CG; ws[WIHT_C+idx]=cWih[g*H3+k]; return; } idx -= H3*CG;
  if (idx < H*G4){ int q=idx&3, r=idx>>2, g=r&511, k4=r>>9; ws[WHHT_W+idx]=wWhh[g*H + 4*k4+q]; return; } idx -= H*G4;
  if (idx < H*G4){ int q=idx&3, r=idx>>2, g=r&511, k4=r>>9; ws[WHHT_V+idx]=vWhh[g*H + 4*k4+q]; return; } idx -= H*G4;
  if (idx < H*G4){ int q=idx&3, r=idx>>2, g=r&511, k4=r>>9; ws[WHHT_A+idx]=aWhh[g*H + 4*k4+q]; return; } idx -= H*G4;
  if (idx < H3*H3){ int k=idx/H3,d=idx%H3; ws[SAT_S+idx]=saW1[d*(2*H3)+k]; return; } idx -= H3*H3;
  if (idx < H3*H3){ int k=idx/H3,d=idx%H3; ws[SAT_T+idx]=saW1[d*(2*H3)+H3+k]; return; } idx -= H3*H3;
  if (idx < H*H){ int k=idx/H,d=idx%H; ws[VW_ST+idx]=vwW1[d*(2*H)+k]; return; } idx -= H*H;
  if (idx < H*H){ int k=idx/H,d=idx%H; ws[VW_TT+idx]=vwW1[d*(2*H)+H+k]; return; } idx -= H*H;
  if (idx < H*H){ int k=idx/H,d=idx%H; ws[AW_ST+idx]=awW1[d*(2*H)+k]; return; } idx -= H*H;
  if (idx < H*H){ int k=idx/H,d=idx%H; ws[AW_TT+idx]=awW1[d*(2*H)+H+k]; return; } idx -= H*H;
  // WRES: c_Whh -> f16x2 in k6's (cell,quarter)-thread layout
  {
    int q4 = idx & 3; int r = idx >> 2;         // uint4 index
    int t = r & 255; int r2 = r >> 8;
    int j = r2 % 48; int sl = r2 / 48;
    int m = t >> 2, q = t & 3;
    int gate = j / 12, ii = j % 12;
    int grow = gate*H3 + sl*64 + m;
    int k2 = q*48 + ii*4 + q4;
    wsu[WRES+idx] = packh2(cWhh[(size_t)grow*H3 + 2*k2], cWhh[(size_t)grow*H3 + 2*k2 + 1]);
  }
}

// ---------------- K1: input projections xg for w/v/a LSTMs ----------------
// grid: 3 * B * (S/8) = 480 blocks, 256 threads
__global__ void k1_xg(float* __restrict__ ws,
    const float* __restrict__ xw, const float* __restrict__ xv, const float* __restrict__ xa)
{
  int bid = blockIdx.x;
  int lstm = bid/160; int rem = bid%160; int b = rem/20; int s0 = (rem%20)*8;
  int in_dim; const float* x; const float* wT; const float* bs; float* xg;
  if (lstm==0){ in_dim=WIN; x=xw; wT=ws+WIHT_W; bs=ws+BSUM_W; xg=ws+XG_W; }
  else if (lstm==1){ in_dim=VIN; x=xv; wT=ws+WIHT_V; bs=ws+BSUM_V; xg=ws+XG_V; }
  else { in_dim=AIN; x=xa; wT=ws+WIHT_A; bs=ws+BSUM_A; xg=ws+XG_A; }
  __shared__ float xt[8][WIN];
  int tid = threadIdx.x;
  for (int i=tid; i<8*in_dim; i+=256){ int r=i/in_dim, k=i%in_dim; xt[r][k] = x[((size_t)(b*S+s0+r))*in_dim + k]; }
  __syncthreads();
  float acc0[8], acc1[8];
  float b0 = bs[tid], b1 = bs[tid+256];
#pragma unroll
  for (int r=0;r<8;r++){ acc0[r]=b0; acc1[r]=b1; }
  for (int k=0;k<in_dim;k++){
    float w0 = wT[k*G4 + tid], w1 = wT[k*G4 + 256 + tid];
#pragma unroll
    for (int r=0;r<8;r++){ float xx = xt[r][k]; acc0[r] = fmaf(xx,w0,acc0[r]); acc1[r] = fmaf(xx,w1,acc1[r]); }
  }
#pragma unroll
  for (int r=0;r<8;r++){
    size_t ro = (size_t)(b*S+s0+r)*G4;
    xg[ro + tid] = acc0[r];
    xg[ro + 256 + tid] = acc1[r];
  }
}

// ---------------- K2: w/v/a LSTM recurrences (one block per lstm,batch) ----------------
// grid 24 blocks, 512 threads; Whh in 32 named float4.
__global__ __launch_bounds__(512,1) void k2_lstm(float* __restrict__ ws)
{
  int lstm = blockIdx.x >> 3, b = blockIdx.x & 7;
  const float* xg; const float* whhT; float* hs; float* cx = nullptr;
  if (lstm==0){ xg=ws+XG_W; whhT=ws+WHHT_W; hs=ws+HS_W; cx=ws+C_X; }
  else if (lstm==1){ xg=ws+XG_V; whhT=ws+WHHT_V; hs=ws+HS_V; }
  else { xg=ws+XG_A; whhT=ws+WHHT_A; hs=ws+HS_A; }
  int g = threadIdx.x;
  const float4* wb = ((const float4*)whhT) + g;
#define K2_LD(i) float4 w##i = wb[(i)*512];
  REP32(K2_LD)
  __shared__ __align__(16) float hbuf[H];
  __shared__ float gsum[G4];
  float c_reg = 0.f;
  if (g < H) hbuf[g] = 0.f;
  const float* xgb = xg + (size_t)b*S*G4;
  float* hsb = hs + (size_t)b*S*H;
  float* cxb = cx ? cx + (size_t)b*S*H3 : nullptr;
  float xg_cur = xgb[g];
  __syncthreads();
  const float4* h4p = (const float4*)hbuf;
  for (int t=0;t<S;t++){
    float acc = xg_cur;
    float xg_nxt = (t+1<S) ? xgb[(size_t)(t+1)*G4 + g] : 0.f;
#define K2_FMA(i) { float4 h4 = h4p[i]; acc = fmaf(w##i.x,h4.x,acc); acc = fmaf(w##i.y,h4.y,acc); acc = fmaf(w##i.z,h4.z,acc); acc = fmaf(w##i.w,h4.w,acc); }
    REP32(K2_FMA)
    gsum[g] = acc;
    xg_cur = xg_nxt;
    __syncthreads();
    if (g < H){
      float gi=gsum[g], gf=gsum[H+g], gg=gsum[2*H+g], go=gsum[3*H+g];
      c_reg = sigf(gf)*c_reg + sigf(gi)*tanhfast(gg);
      float h = sigf(go)*tanhfast(c_reg);
      hbuf[g] = h;
      hsb[(size_t)t*H + g] = h;
      if (cxb) cxb[(size_t)t*H3 + g] = h;
    }
    __syncthreads();
  }
}

// ---------------- K3a: attention projections (s/t for vw and aw) ----------------
// grid 4*B*(S/8)=640, 128 threads
__global__ void k3a_proj(float* __restrict__ ws, const float* __restrict__ vwb1, const float* __restrict__ awb1)
{
  int bid = blockIdx.x;
  int p = bid/160; int rem = bid%160; int b = rem/20; int s0 = (rem%20)*8;
  const float* src; const float* wT; const float* bias=nullptr; float* dst;
  if (p==0){ src=ws+HS_V; wT=ws+VW_ST; dst=ws+S_VW; }
  else if (p==1){ src=ws+HS_W; wT=ws+VW_TT; bias=vwb1; dst=ws+T_VW; }
  else if (p==2){ src=ws+HS_A; wT=ws+AW_ST; dst=ws+S_AW; }
  else { src=ws+HS_W; wT=ws+AW_TT; bias=awb1; dst=ws+T_AW; }
  __shared__ float xr[8][H];
  int tid = threadIdx.x;
  for (int i=tid;i<8*H;i+=128){ int r=i>>7, k=i&127; xr[r][k] = src[(size_t)(b*S+s0+r)*H + k]; }
  __syncthreads();
  float acc[8];
  float bv = bias ? bias[tid] : 0.f;
#pragma unroll
  for (int r=0;r<8;r++) acc[r]=bv;
  for (int k=0;k<H;k++){
    float wv = wT[k*H + tid];
#pragma unroll
    for (int r=0;r<8;r++) acc[r] = fmaf(xr[r][k], wv, acc[r]);
  }
#pragma unroll
  for (int r=0;r<8;r++) dst[(size_t)(b*S+s0+r)*H + tid] = acc[r];
}

// ---------------- K3b: vw/aw cross-attention (scores, softmax, out) ----------------
// grid 2*B*S/4 = 640 blocks of 256 (wave per (A,b,w) row)
__global__ void k3b_attn(float* __restrict__ ws, float* __restrict__ dout,
    const int* __restrict__ lengths, const float* __restrict__ vww2, const float* __restrict__ aww2)
{
  int wid = threadIdx.x >> 6, lane = threadIdx.x & 63;
  int row = blockIdx.x*4 + wid;
  int A = row / (B*S); int rem = row % (B*S); int b = rem / S; int w = rem % S;
  const float* sp = ws + (A? S_AW : S_VW) + (size_t)(b*S)*H;
  const float* tp = ws + (A? T_AW : T_VW) + (size_t)(b*S + w)*H;
  const float* w2 = A? aww2 : vww2;
  const float* src = ws + (A? HS_A : HS_V) + (size_t)(b*S)*H;
  float* attw = dout + (A? O_AATT : O_VATT) + (size_t)b*S*S + (size_t)w*S;
  int len = lengths[b];
  __shared__ float sc[4][S];
  float2 t2 = ((const float2*)tp)[lane];
  float2 w22 = ((const float2*)w2)[lane];
  for (int v=0; v<S; v++){
    float2 s2 = ((const float2*)(sp + (size_t)v*H))[lane];
    float x0 = tanhfast(t2.x + s2.x), x1 = tanhfast(t2.y + s2.y);
    float p = wred_sum(x0*w22.x + x1*w22.y);
    if (lane==0) sc[wid][v] = p;
  }
  __syncthreads();
  float m0 = (lane      < len)? sc[wid][lane]     : 0.f;
  float m1 = (lane+64   < len)? sc[wid][lane+64]  : 0.f;
  float m2 = (lane<32) ? ((lane+128 < len)? sc[wid][lane+128] : 0.f) : -1e30f;
  float m = wred_max(fmaxf(fmaxf(m0,m1),m2));
  float e0 = __expf(m0-m), e1 = __expf(m1-m), e2 = (lane<32)? __expf(m2-m) : 0.f;
  float inv = 1.f / wred_sum(e0+e1+e2);
  e0*=inv; e1*=inv; e2*=inv;
  sc[wid][lane] = e0; sc[wid][lane+64] = e1; if (lane<32) sc[wid][128+lane] = e2;
  attw[lane] = e0; attw[lane+64] = e1; if (lane<32) attw[128+lane] = e2;
  __syncthreads();
  float2 acc; acc.x=0.f; acc.y=0.f;
  for (int v=0; v<S; v++){
    float wg = sc[wid][v];
    float2 sv = ((const float2*)(src + (size_t)v*H))[lane];
    acc.x = fmaf(wg, sv.x, acc.x); acc.y = fmaf(wg, sv.y, acc.y);
  }
  float* cxr = ws + C_X + (size_t)(b*S + w)*H3 + (A? 2*H : H);
  ((float2*)cxr)[lane] = acc;
}

// ---------------- K4: soft attention (v and a) ----------------
// grid 16 (A*8+b), 256 threads
__global__ void k4_soft(float* __restrict__ ws, float* __restrict__ dout,
    const float* __restrict__ mpw, const float* __restrict__ mpb)
{
  int A = blockIdx.x >> 3, b = blockIdx.x & 7;
  const float* reps = ws + (A? HS_A : HS_V) + (size_t)(b*S)*H;
  float* softw = dout + (A? O_ASOFT : O_VSOFT) + b*S;
  float* comp = ws + (A? ACOMP : VCOMP) + b*H;
  __shared__ float sc[S]; __shared__ float wg[S];
  int wid = threadIdx.x >> 6, lane = threadIdx.x & 63;
  float bb = mpb[0];
  for (int s=wid; s<S; s+=4){
    float2 r2 = ((const float2*)(reps + (size_t)s*H))[lane];
    float2 m2 = ((const float2*)mpw)[lane];
    float p = wred_sum(r2.x*m2.x + r2.y*m2.y);
    if (lane==0) sc[s] = p + bb;
  }
  __syncthreads();
  if (threadIdx.x < 64){
    float m0 = sc[lane], m1 = sc[lane+64], m2 = (lane<32)? sc[lane+128] : -1e30f;
    float m = wred_max(fmaxf(fmaxf(m0,m1),m2));
    float e0=__expf(m0-m), e1=__expf(m1-m), e2=(lane<32)?__expf(m2-m):0.f;
    float inv = 1.f / wred_sum(e0+e1+e2);
    e0*=inv; e1*=inv; e2*=inv;
    wg[lane]=e0; wg[lane+64]=e1; if (lane<32) wg[128+lane]=e2;
    softw[lane]=e0; softw[lane+64]=e1; if (lane<32) softw[128+lane]=e2;
  }
  __syncthreads();
  if (threadIdx.x < H){
    float acc=0.f;
    for (int s=0;s<S;s++) acc = fmaf(wg[s], reps[(size_t)s*H + threadIdx.x], acc);
    comp[threadIdx.x] = acc;
  }
}

// ---------------- K5: c-LSTM input projection -> xgc [b][t][gate] f16 ----------------
// grid B*40 (s-tile 4), 512 threads
__global__ void k5_xgc(float* __restrict__ ws, u32* __restrict__ wsu)
{
  int b = blockIdx.x/40; int s0 = (blockIdx.x%40)*4;
  const float* cxb = ws + C_X + (size_t)(b*S+s0)*H3;
  const float* wT = ws + WIHT_C;
  const float* bs = ws + BSUM_C;
  __half* xgc = (__half*)(wsu + XGC16);
  __shared__ float xr[4][H3];
  int tid = threadIdx.x;
  for (int i=tid;i<4*H3;i+=512){ int r=i/H3, k=i%H3; xr[r][k]=cxb[(size_t)r*H3+k]; }
  __syncthreads();
  float acc[4][3];
  float b0=bs[tid], b1=bs[tid+512], b2=bs[tid+1024];
#pragma unroll
  for (int r=0;r<4;r++){ acc[r][0]=b0; acc[r][1]=b1; acc[r][2]=b2; }
  for (int k=0;k<H3;k++){
    float w0=wT[(size_t)k*CG+tid], w1=wT[(size_t)k*CG+512+tid], w2v=wT[(size_t)k*CG+1024+tid];
#pragma unroll
    for (int r=0;r<4;r++){
      float xx = xr[r][k];
      acc[r][0]=fmaf(xx,w0,acc[r][0]); acc[r][1]=fmaf(xx,w1,acc[r][1]); acc[r][2]=fmaf(xx,w2v,acc[r][2]);
    }
  }
#pragma unroll
  for (int r=0;r<4;r++){
    size_t ro = (size_t)(b*S + s0+r)*CG;
    xgc[ro + tid]        = __float2half_rn(acc[r][0]);
    xgc[ro + 512 + tid]  = __float2half_rn(acc[r][1]);
    xgc[ro + 1024 + tid] = __float2half_rn(acc[r][2]);
  }
}

// ---------------- K6: c-LSTM recurrence ----------------
// 48 blocks = sl*8 + b. 256 threads (1 wave/SIMD -> 256-VGPR budget).
// Thread (m=tid>>2, q=tid&3): cell sl*64+m, dim-quarter q (96 dims), 4 gates
// = 48 named uint4 (192 VGPR). Gates completed via 2x shfl_xor across q — no
// LDS gsum phase; all 256 threads update c,h (replicated x4, deterministic).
// Publish: 32 lanes (tid&7==0) atomic-store seq-tagged u64; 160 pollers spin
// with s_sleep backoff (traffic-throttled). Monotone seq + parity => race-free,
// re-poison-safe.
__global__ __launch_bounds__(256,1) void k6_clstm(float* __restrict__ ws, u32* __restrict__ wsu)
{
  int b = blockIdx.x & 7, sl = blockIdx.x >> 3;
  int tid = threadIdx.x, m = tid>>2, q = tid&3;
  const __half* xgb = ((const __half*)(wsu + XGC16)) + (size_t)b*S*CG;
  u32* chsb = wsu + CHS16 + (size_t)b*S*(H3/2);
  u64* slots = (u64*)(wsu + H_X);   // [par][b][192]
  const uint4* wb = ((const uint4*)(wsu + WRES)) + (size_t)sl*48*256 + tid;
#define K6_LD(i) uint4 w##i = wb[(i)*256];
  REP48(K6_LD)
  __shared__ __align__(16) u32 h2[H3/2];
  float c_reg = 0.f;
  if (tid < H3/2) h2[tid] = 0u;
  int cell = sl*64 + m;
  const __half* xga = xgb + cell;   // + gate*H3 + t*CG
  float xi = __half2float(xga[0]);
  float xf = __half2float(xga[H3]);
  float xg_ = __half2float(xga[2*H3]);
  float xo = __half2float(xga[3*H3]);
  __syncthreads();
  const uint4* h2q = ((const uint4*)h2) + q*12;
  for (int t=0;t<S;t++){
    // prefetch next-step xg (consumed next iteration)
    float ni=0.f,nf=0.f,ng=0.f,no=0.f;
    if (t+1 < S){
      const __half* xn = xga + (size_t)(t+1)*CG;
      ni=__half2float(xn[0]); nf=__half2float(xn[H3]); ng=__half2float(xn[2*H3]); no=__half2float(xn[3*H3]);
    }
    float a0=0.f,a1=0.f,a2=0.f,a3=0.f;
#define K6_I(i, wA,wB,wC,wD) { uint4 hh = h2q[i]; \
    a0=fdot2f(wA.x,hh.x,a0); a0=fdot2f(wA.y,hh.y,a0); a0=fdot2f(wA.z,hh.z,a0); a0=fdot2f(wA.w,hh.w,a0); \
    a1=fdot2f(wB.x,hh.x,a1); a1=fdot2f(wB.y,hh.y,a1); a1=fdot2f(wB.z,hh.z,a1); a1=fdot2f(wB.w,hh.w,a1); \
    a2=fdot2f(wC.x,hh.x,a2); a2=fdot2f(wC.y,hh.y,a2); a2=fdot2f(wC.z,hh.z,a2); a2=fdot2f(wC.w,hh.w,a2); \
    a3=fdot2f(wD.x,hh.x,a3); a3=fdot2f(wD.y,hh.y,a3); a3=fdot2f(wD.z,hh.z,a3); a3=fdot2f(wD.w,hh.w,a3); }
    K6_I(0,  w0,  w12, w24, w36)
    K6_I(1,  w1,  w13, w25, w37)
    K6_I(2,  w2,  w14, w26, w38)
    K6_I(3,  w3,  w15, w27, w39)
    K6_I(4,  w4,  w16, w28, w40)
    K6_I(5,  w5,  w17, w29, w41)
    K6_I(6,  w6,  w18, w30, w42)
    K6_I(7,  w7,  w19, w31, w43)
    K6_I(8,  w8,  w20, w32, w44)
    K6_I(9,  w9,  w21, w33, w45)
    K6_I(10, w10, w22, w34, w46)
    K6_I(11, w11, w23, w35, w47)
    __syncthreads();   // A: all h2 reads of step t done
    // reduce across the 4 dim-quarters (lanes differing in bits 0-1)
    a0 += __shfl_xor(a0,1); a0 += __shfl_xor(a0,2);
    a1 += __shfl_xor(a1,1); a1 += __shfl_xor(a1,2);
    a2 += __shfl_xor(a2,1); a2 += __shfl_xor(a2,2);
    a3 += __shfl_xor(a3,1); a3 += __shfl_xor(a3,2);
    float gi = a0 + xi, gf = a1 + xf, gg = a2 + xg_, go = a3 + xo;
    c_reg = sigf(gf)*c_reg + sigf(gi)*tanhfast(gg);
    float h = sigf(go)*tanhfast(c_reg);
    int par = t & 1;
    u32 target = (u32)(t>>1) + 1u;
    u64* sb = slots + ((size_t)par*8 + b)*192;
    float h1 = __shfl_down(h, 4);   // cell m+1's h (q=0 lane)
    if ((tid & 7) == 0){
      u32 pk = packh2(h, h1);
      int p = sl*32 + (tid>>3);
      h2[p] = pk;
      if (t+1 < S)
        __hip_atomic_store(&sb[p], ((u64)target<<32) | (u64)pk,
                           __ATOMIC_RELAXED, __HIP_MEMORY_SCOPE_AGENT);
      chsb[(size_t)t*(H3/2) + p] = pk;
    }
    if (t+1 < S && tid >= 64 && tid < 224){
      int i = tid - 64;
      int pi = i >> 5;
      int psl = sl + 1 + pi; if (psl >= 6) psl -= 6;
      int p = psl*32 + (i & 31);
      u64 v = __hip_atomic_load(&sb[p], __ATOMIC_RELAXED, __HIP_MEMORY_SCOPE_AGENT);
      while ((u32)(v>>32) != target){
        __builtin_amdgcn_s_sleep(1);
        v = __hip_atomic_load(&sb[p], __ATOMIC_RELAXED, __HIP_MEMORY_SCOPE_AGENT);
      }
      h2[p] = (u32)v;
    }
    xi=ni; xf=nf; xg_=ng; xo=no;
    __syncthreads();   // B: h2 ready for step t+1
  }
}

// ---------------- K7a: sa source projection s_sa = c_hs @ saW1[:, :H3].T ----------------
// grid B*40 (v-tile 4), 384 threads
__global__ void k7a_sproj(float* __restrict__ ws, u32* __restrict__ wsu)
{
  int b = blockIdx.x/40; int v0 = (blockIdx.x%40)*4;
  const __half* chs = (const __half*)(wsu + CHS16);
  const float* wT = ws + SAT_S;
  __shared__ float xr[4][H3];
  int tid = threadIdx.x;
  for (int i=tid;i<4*H3;i+=384){ int r=i/H3, k=i%H3; xr[r][k] = __half2float(chs[(size_t)(b*S+v0+r)*H3 + k]); }
  __syncthreads();
  float acc[4] = {0.f,0.f,0.f,0.f};
  for (int k=0;k<H3;k++){
    float wv = wT[(size_t)k*H3 + tid];
#pragma unroll
    for (int r=0;r<4;r++) acc[r] = fmaf(xr[r][k], wv, acc[r]);
  }
#pragma unroll
  for (int r=0;r<4;r++) ws[S_SA + (size_t)(b*S+v0+r)*H3 + tid] = acc[r];
}

// ---------------- K7b: sa attention at the single needed row (lengths-1) ----------------
// grid B, 384 threads (6 waves)
__global__ void k7b_sa(float* __restrict__ ws, u32* __restrict__ wsu,
    const int* __restrict__ lengths, const float* __restrict__ sab1, const float* __restrict__ saw2)
{
  int b = blockIdx.x;
  int len = lengths[b]; int tr = len-1;
  const __half* chs = (const __half*)(wsu + CHS16);
  __shared__ float tv[H3]; __shared__ float chr[H3]; __shared__ float sc[S]; __shared__ float wg[S];
  int tid = threadIdx.x, wid = tid>>6, lane = tid&63;
  chr[tid] = __half2float(chs[(size_t)(b*S+tr)*H3 + tid]);
  __syncthreads();
  float acc = sab1[tid];
  for (int k=0;k<H3;k++) acc = fmaf(chr[k], ws[SAT_T + (size_t)k*H3 + tid], acc);
  tv[tid] = acc;
  __syncthreads();
  for (int v=wid; v<S; v+=6){
    const float* sr = ws + S_SA + (size_t)(b*S+v)*H3;
    float p = 0.f;
#pragma unroll
    for (int q=0;q<6;q++){
      int d = lane + 64*q;
      p = fmaf(tanhfast(tv[d] + sr[d]), saw2[d], p);
    }
    p = wred_sum(p);
    if (lane==0) sc[v] = p;
  }
  __syncthreads();
  if (tid < 64){
    float m0 = (lane<len)? sc[lane]:0.f;
    float m1 = (lane+64<len)? sc[lane+64]:0.f;
    float m2 = (lane<32)? ((lane+128<len)? sc[lane+128]:0.f) : -1e30f;
    float m = wred_max(fmaxf(fmaxf(m0,m1),m2));
    float e0=__expf(m0-m), e1=__expf(m1-m), e2=(lane<32)?__expf(m2-m):0.f;
    float inv = 1.f / wred_sum(e0+e1+e2);
    wg[lane]=e0*inv; wg[lane+64]=e1*inv; if (lane<32) wg[128+lane]=e2*inv;
  }
  __syncthreads();
  float o = 0.f;
  for (int v=0; v<S; v++) o = fmaf(wg[v], __half2float(chs[(size_t)(b*S+v)*H3 + tid]), o);
  ws[C_OUT + (size_t)b*H3 + tid] = o;
}

// ---------------- K8: final MLP ----------------
// grid B, 128 threads
__global__ void k8_mlp(float* __restrict__ ws, float* __restrict__ dout,
    const float* __restrict__ fc1W, const float* __restrict__ fc1b,
    const float* __restrict__ fc2W, const float* __restrict__ fc2b)
{
  int b = blockIdx.x, tid = threadIdx.x;
  __shared__ float feat[5*H]; __shared__ float r1[H];
  for (int i=tid;i<5*H;i+=128){
    float val;
    if (i < H3) val = ws[C_OUT + (size_t)b*H3 + i];
    else if (i < H3+H) val = ws[VCOMP + b*H + (i-H3)];
    else val = ws[ACOMP + b*H + (i-H3-H)];
    feat[i] = val;
  }
  __syncthreads();
  float acc = fc1b[tid];
  for (int k=0;k<5*H;k++) acc = fmaf(feat[k], fc1W[(size_t)tid*5*H + k], acc);
  r1[tid] = fmaxf(acc, 0.f) * fc2W[tid];
  __syncthreads();
  if (tid < 64){
    float p = r1[tid] + r1[tid+64];
    p = wred_sum(p);
    if (tid==0) dout[b] = p + fc2b[0];
  }
}

// ---------------- launch ----------------
extern "C" void kernel_launch(void* const* d_in, const int* in_sizes, int n_in,
                              void* d_out, int out_size, void* d_ws, size_t ws_size,
                              hipStream_t stream) {
  const float* xw = (const float*)d_in[0];
  const float* xv = (const float*)d_in[1];
  const float* xa = (const float*)d_in[2];
  const int* lengths = (const int*)d_in[3];
  const float* wWih=(const float*)d_in[4], *wWhh=(const float*)d_in[5], *wbih=(const float*)d_in[6], *wbhh=(const float*)d_in[7];
  const float* vWih=(const float*)d_in[8], *vWhh=(const float*)d_in[9], *vbih=(const float*)d_in[10], *vbhh=(const float*)d_in[11];
  const float* aWih=(const float*)d_in[12], *aWhh=(const float*)d_in[13], *abih=(const float*)d_in[14], *abhh=(const float*)d_in[15];
  const float* cWih=(const float*)d_in[16], *cWhh=(const float*)d_in[17], *cbih=(const float*)d_in[18], *cbhh=(const float*)d_in[19];
  const float* vwW1=(const float*)d_in[20], *vwb1=(const float*)d_in[21], *vww2=(const float*)d_in[22];
  const float* awW1=(const float*)d_in[23], *awb1=(const float*)d_in[24], *aww2=(const float*)d_in[25];
  const float* saW1=(const float*)d_in[26], *sab1=(const float*)d_in[27], *saw2=(const float*)d_in[28];
  const float* mpw=(const float*)d_in[29], *mpb=(const float*)d_in[30];
  const float* fc1W=(const float*)d_in[31], *fc1b=(const float*)d_in[32];
  const float* fc2W=(const float*)d_in[33], *fc2b=(const float*)d_in[34];
  float* ws = (float*)d_ws;
  u32* wsu = (u32*)d_ws;
  float* dout = (float*)d_out;

  hipLaunchKernelGGL(k0_prep, dim3((PREP_TOT+255)/256), dim3(256), 0, stream,
      ws, wsu, wWih,wWhh,wbih,wbhh, vWih,vWhh,vbih,vbhh, aWih,aWhh,abih,abhh,
      cWih,cWhh,cbih,cbhh, vwW1, awW1, saW1);
  hipLaunchKernelGGL(k1_xg, dim3(480), dim3(256), 0, stream, ws, xw, xv, xa);
  hipLaunchKernelGGL(k2_lstm, dim3(24), dim3(512), 0, stream, ws);
  hipLaunchKernelGGL(k3a_proj, dim3(640), dim3(128), 0, stream, ws, vwb1, awb1);
  hipLaunchKernelGGL(k3b_attn, dim3(640), dim3(256), 0, stream, ws, dout, lengths, vww2, aww2);
  hipLaunchKernelGGL(k4_soft, dim3(16), dim3(256), 0, stream, ws, dout, mpw, mpb);
  hipLaunchKernelGGL(k5_xgc, dim3(B*40), dim3(512), 0, stream, ws, wsu);
  hipLaunchKernelGGL(k6_clstm, dim3(48), dim3(256), 0, stream, ws, wsu);
  hipLaunchKernelGGL(k7a_sproj, dim3(B*40), dim3(384), 0, stream, ws, wsu);
  hipLaunchKernelGGL(k7b_sa, dim3(B), dim3(384), 0, stream, ws, wsu, lengths, sab1, saw2);
  hipLaunchKernelGGL(k8_mlp, dim3(B), dim3(128), 0, stream, ws, dout, fc1W, fc1b, fc2W, fc2b);
}